// Round 12
// baseline (2556.907 us; speedup 1.0000x reference)
//
#include <hip/hip_runtime.h>

#define HD 128   // hidden dim

typedef unsigned short ushort_t;
typedef __attribute__((ext_vector_type(8))) unsigned short us8;
typedef __attribute__((ext_vector_type(8))) short s8b;       // 8 bf16 = 4 VGPR (MFMA A/B frag)
typedef __attribute__((ext_vector_type(16))) float f32x16;   // MFMA 32x32 accumulator

// ---------------- bf16 <-> f32 ----------------
__device__ __forceinline__ float b2f(unsigned short u) {
    union { unsigned int i; float f; } v; v.i = ((unsigned int)u) << 16; return v.f;
}
__device__ __forceinline__ unsigned short f2b(float f) {
    union { float f; unsigned int i; } v; v.f = f;
    unsigned int u = v.i;
    return (unsigned short)((u + 0x7fffu + ((u >> 16) & 1u)) >> 16);  // RNE
}

__device__ __forceinline__ void load8f(const float* p, float* o) {
    float4 a = *reinterpret_cast<const float4*>(p);
    float4 b = *reinterpret_cast<const float4*>(p + 4);
    o[0]=a.x;o[1]=a.y;o[2]=a.z;o[3]=a.w;o[4]=b.x;o[5]=b.y;o[6]=b.z;o[7]=b.w;
}
__device__ __forceinline__ void load8b(const ushort_t* p, float* o) {
    us8 v = *reinterpret_cast<const us8*>(p);
#pragma unroll
    for (int j = 0; j < 8; ++j) o[j] = b2f(v[j]);
}
__device__ __forceinline__ void store8b(ushort_t* p, const float* s) {
    us8 v;
#pragma unroll
    for (int j = 0; j < 8; ++j) v[j] = f2b(s[j]);
    *reinterpret_cast<us8*>(p) = v;
}

__device__ __forceinline__ void store1(float* p, float v) { *p = v; }
__device__ __forceinline__ void store1(ushort_t* p, float v) { *p = f2b(v); }

__device__ __forceinline__ int lowerb(const int* __restrict__ a, int n, int v) {
    int lo = 0, hi = n;
    while (lo < hi) { int m = (lo + hi) >> 1; if (a[m] < v) lo = m + 1; else hi = m; }
    return lo;
}

// ---------------- CSR build ----------------
__global__ void hist_kernel(const int* __restrict__ dst, int* __restrict__ deg, int e) {
    int i = blockIdx.x * blockDim.x + threadIdx.x;
    if (i < e) atomicAdd(&deg[dst[i]], 1);
}

#define SCAN_NT 256
#define SCAN_BPT 8
#define SCAN_CHUNK (SCAN_NT * SCAN_BPT)   // 2048

__global__ __launch_bounds__(SCAN_NT) void scan_a(const int* __restrict__ deg,
                                                  int* __restrict__ bsum, int n) {
    int tid = threadIdx.x;
    int base = blockIdx.x * SCAN_CHUNK + tid * SCAN_BPT;
    int sum = 0;
    if (base + SCAN_BPT <= n) {
        int4 v0 = *reinterpret_cast<const int4*>(deg + base);
        int4 v1 = *reinterpret_cast<const int4*>(deg + base + 4);
        sum = v0.x + v0.y + v0.z + v0.w + v1.x + v1.y + v1.z + v1.w;
    } else {
        for (int j = 0; j < SCAN_BPT; ++j) { int i = base + j; if (i < n) sum += deg[i]; }
    }
    __shared__ int sd[SCAN_NT];
    sd[tid] = sum; __syncthreads();
    for (int off = SCAN_NT / 2; off > 0; off >>= 1) {
        if (tid < off) sd[tid] += sd[tid + off];
        __syncthreads();
    }
    if (tid == 0) bsum[blockIdx.x] = sd[0];
}

__global__ __launch_bounds__(1024) void scan_b(int* __restrict__ bsum, int nb) {
    __shared__ int ps[1024];
    int tid = threadIdx.x;
    int v = (tid < nb) ? bsum[tid] : 0;
    ps[tid] = v; __syncthreads();
    for (int off = 1; off < 1024; off <<= 1) {
        int t = (tid >= off) ? ps[tid - off] : 0;
        __syncthreads();
        ps[tid] += t;
        __syncthreads();
    }
    if (tid < nb) bsum[tid] = ps[tid] - v;   // exclusive block offsets
}

__global__ __launch_bounds__(SCAN_NT) void scan_c(const int* __restrict__ deg,
                                                  const int* __restrict__ bsum,
                                                  int* __restrict__ rowptr,
                                                  int* __restrict__ cursor,
                                                  int n, int etot) {
    int tid = threadIdx.x;
    int base = blockIdx.x * SCAN_CHUNK + tid * SCAN_BPT;
    int vals[SCAN_BPT];
    if (base + SCAN_BPT <= n) {
        int4 v0 = *reinterpret_cast<const int4*>(deg + base);
        int4 v1 = *reinterpret_cast<const int4*>(deg + base + 4);
        vals[0]=v0.x; vals[1]=v0.y; vals[2]=v0.z; vals[3]=v0.w;
        vals[4]=v1.x; vals[5]=v1.y; vals[6]=v1.z; vals[7]=v1.w;
    } else {
        for (int j = 0; j < SCAN_BPT; ++j) { int i = base + j; vals[j] = (i < n) ? deg[i] : 0; }
    }
    int sum = 0;
#pragma unroll
    for (int j = 0; j < SCAN_BPT; ++j) sum += vals[j];
    __shared__ int ps[SCAN_NT];
    ps[tid] = sum; __syncthreads();
    for (int off = 1; off < SCAN_NT; off <<= 1) {
        int t = (tid >= off) ? ps[tid - off] : 0;
        __syncthreads();
        ps[tid] += t;
        __syncthreads();
    }
    int run = bsum[blockIdx.x] + ps[tid] - sum;
#pragma unroll
    for (int j = 0; j < SCAN_BPT; ++j) {
        int i = base + j;
        if (i < n) { rowptr[i] = run; cursor[i] = run; run += vals[j]; }
    }
    if (blockIdx.x == 0 && tid == 0) rowptr[n] = etot;
}

__global__ void fill_kernel(const int* __restrict__ src, const int* __restrict__ dst,
                            int* __restrict__ cursor, int* __restrict__ col, int e) {
    int i = blockIdx.x * blockDim.x + threadIdx.x;
    if (i < e) { int slot = atomicAdd(&cursor[dst[i]], 1); col[slot] = src[i]; }
}

// ---------------- W pre-pack into MFMA B-fragment order (bf16) ----------------
// flat idx = ((mat*4 + j)*8 + ks)*64 + lane; elem e = W[ks*16+(lane>>5)*8+e][mat*col_off + j*32 + (lane&31)]
// NOTE: B-frag(W) is bit-identical to A-frag(W^T) — used by the swapped GEMM1.
__global__ void pack_kernel(const float* __restrict__ W, ushort_t* __restrict__ Wp,
                            int nmat, int ld, int mat_stride, int col_off) {
    int idx = blockIdx.x * blockDim.x + threadIdx.x;
    if (idx >= nmat * 2048) return;
    int lane = idx & 63;
    int ks = (idx >> 6) & 7;
    int j = (idx >> 9) & 3;
    int mat = idx >> 11;
    const float* Wm = W + (size_t)mat * mat_stride;
    int k0 = ks * 16 + (lane >> 5) * 8;
    int n = mat * col_off + j * 32 + (lane & 31);
    us8 o;
#pragma unroll
    for (int e = 0; e < 8; ++e) o[e] = f2b(Wm[(size_t)(k0 + e) * ld + n]);
    *reinterpret_cast<us8*>(Wp + (size_t)idx * 8) = o;
}

// ---------------- fused x-aggregation: xa[node] = {x[node] + Σ_nbr x[nbr], 1+deg} ----------------
__global__ void xagg_kernel(const float* __restrict__ x, const int* __restrict__ rowptr,
                            const int* __restrict__ col, float* __restrict__ xa, int n) {
    int node = blockIdx.x * blockDim.x + threadIdx.x;
    if (node >= n) return;
    const float2* xr = reinterpret_cast<const float2*>(x + (size_t)node * 6);
    float2 a0 = xr[0], a1 = xr[1], a2 = xr[2];
    int lo = rowptr[node], hi = rowptr[node + 1];
    for (int i = lo; i < hi; ++i) {
        const float2* xs = reinterpret_cast<const float2*>(x + (size_t)col[i] * 6);
        float2 s0 = xs[0], s1 = xs[1], s2 = xs[2];
        a0.x += s0.x; a0.y += s0.y; a1.x += s1.x; a1.y += s1.y; a2.x += s2.x; a2.y += s2.y;
    }
    float cnt = (float)(1 + hi - lo);
    float4 o0; o0.x = a0.x; o0.y = a0.y; o0.z = a1.x; o0.w = a1.y;
    float4 o1; o1.x = a2.x; o1.y = a2.y; o1.z = cnt; o1.w = 0.f;
    reinterpret_cast<float4*>(xa + (size_t)node * 8)[0] = o0;
    reinterpret_cast<float4*>(xa + (size_t)node * 8)[1] = o1;
}

// ---------------- encoder v2: z1 = xa[:, :6] @ W_enc + xa[:,6]·b_enc  (bf16 out) ----------------
__global__ void enc2_kernel(const float* __restrict__ xa, const float* __restrict__ W,
                            const float* __restrict__ b, ushort_t* __restrict__ z, int n) {
    int t = blockIdx.x * blockDim.x + threadIdx.x;
    int q = t >> 4, g = t & 15;
    int node0 = q * 4;
    if (node0 >= n) return;
    float w[6][8];
#pragma unroll
    for (int d = 0; d < 6; ++d) load8f(W + d * HD + g * 8, w[d]);
    float bias[8];
    load8f(b + g * 8, bias);
#pragma unroll
    for (int u = 0; u < 4; ++u) {
        int node = node0 + u;
        if (node >= n) break;
        float4 a0 = reinterpret_cast<const float4*>(xa + (size_t)node * 8)[0];
        float4 a1 = reinterpret_cast<const float4*>(xa + (size_t)node * 8)[1];
        float xv[6] = {a0.x, a0.y, a0.z, a0.w, a1.x, a1.y};
        float cnt = a1.z;
        float acc[8];
#pragma unroll
        for (int j = 0; j < 8; ++j) acc[j] = cnt * bias[j];
#pragma unroll
        for (int d = 0; d < 6; ++d)
#pragma unroll
            for (int j = 0; j < 8; ++j) acc[j] += xv[d] * w[d][j];
        store8b(z + (size_t)node * HD + g * 8, acc);
    }
}

// ---------------- GEMM1(swapped)+repack and GEMM2 helpers (shared by mlp/gin kernels) ----------------
__device__ __forceinline__ void gemm1_repack(const s8b* __restrict__ sW, const s8b* bz,
                                             const float* __restrict__ b1,
                                             int lane, int h, s8b* a2) {
#pragma unroll
    for (int j = 0; j < 4; ++j) {
        f32x16 c;
#pragma unroll
        for (int i = 0; i < 16; ++i) c[i] = 0.f;
#pragma unroll
        for (int ks = 0; ks < 8; ++ks)
            c = __builtin_amdgcn_mfma_f32_32x32x16_bf16(sW[(j * 8 + ks) * 64 + lane], bz[ks], c, 0, 0, 0);
        unsigned int w[4][2];
#pragma unroll
        for (int b = 0; b < 4; ++b) {
            float4 bv = *reinterpret_cast<const float4*>(b1 + j * 32 + b * 8 + 4 * h);
            float v0 = fmaxf(c[4 * b + 0] + bv.x, 0.f);
            float v1 = fmaxf(c[4 * b + 1] + bv.y, 0.f);
            float v2 = fmaxf(c[4 * b + 2] + bv.z, 0.f);
            float v3 = fmaxf(c[4 * b + 3] + bv.w, 0.f);
            w[b][0] = (unsigned int)f2b(v0) | ((unsigned int)f2b(v1) << 16);
            w[b][1] = (unsigned int)f2b(v2) | ((unsigned int)f2b(v3) << 16);
        }
        unsigned int p[4][2];
#pragma unroll
        for (int b = 0; b < 4; ++b) {
            p[b][0] = (unsigned int)__shfl_xor((int)w[b][0], 32);
            p[b][1] = (unsigned int)__shfl_xor((int)w[b][1], 32);
        }
        union { unsigned int u[4]; s8b v; } t0, t1;
        t0.u[0] = (h == 0) ? w[0][0] : p[1][0];
        t0.u[1] = (h == 0) ? w[0][1] : p[1][1];
        t0.u[2] = (h == 0) ? p[0][0] : w[1][0];
        t0.u[3] = (h == 0) ? p[0][1] : w[1][1];
        t1.u[0] = (h == 0) ? w[2][0] : p[3][0];
        t1.u[1] = (h == 0) ? w[2][1] : p[3][1];
        t1.u[2] = (h == 0) ? p[2][0] : w[3][0];
        t1.u[3] = (h == 0) ? p[2][1] : w[3][1];
        a2[2 * j]     = t0.v;
        a2[2 * j + 1] = t1.v;
    }
}

__device__ __forceinline__ void gemm2_store(const s8b* __restrict__ sW, const s8b* a2,
                                            const float* __restrict__ b2,
                                            int lane, int h, int row0,
                                            ushort_t* __restrict__ out) {
    const int r32 = lane & 31;
#pragma unroll
    for (int j = 0; j < 4; ++j) {
        f32x16 c;
#pragma unroll
        for (int i = 0; i < 16; ++i) c[i] = 0.f;
#pragma unroll
        for (int ks = 0; ks < 8; ++ks)
            c = __builtin_amdgcn_mfma_f32_32x32x16_bf16(a2[ks], sW[(j * 8 + ks) * 64 + lane], c, 0, 0, 0);
        const int ccol = j * 32 + r32;
        const float bv = b2[ccol];
        const int rbase = row0 + 4 * h;
#pragma unroll
        for (int reg = 0; reg < 16; ++reg) {
            int row = rbase + (reg & 3) + 8 * (reg >> 2);
            out[(size_t)row * HD + ccol] = f2b(fmaxf(c[reg] + bv, 0.f));
        }
    }
}

// ---------------- fused GIN MLP (layer 1): z <- relu(relu(z@W1+b1)@W2+b2)  IN-PLACE ----------------
// 32 KB LDS, W1 then W2 staged into the SAME buffer -> 4 blocks/CU, VGPR<=64 (8 waves/SIMD).
__global__ __launch_bounds__(512, 8) void mlp_fused(
    ushort_t* __restrict__ z,
    const ushort_t* __restrict__ Wp1, const ushort_t* __restrict__ Wp2,
    const float* __restrict__ b1, const float* __restrict__ b2)
{
    __shared__ s8b sW[2048];   // 32 KB, reused for W1 then W2

    const int tid = threadIdx.x;
    for (int i = tid; i < 2048; i += 512)
        sW[i] = reinterpret_cast<const s8b*>(Wp1)[i];

    const int lane = tid & 63;
    const int r32  = lane & 31;
    const int h    = lane >> 5;
    const int row0 = blockIdx.x * 256 + (tid >> 6) * 32;
    const int arow = row0 + r32;
    const int koff = h * 8;

    s8b bz[8];
#pragma unroll
    for (int ks = 0; ks < 8; ++ks)
        bz[ks] = *reinterpret_cast<const s8b*>(z + (size_t)arow * HD + ks * 16 + koff);

    __syncthreads();            // W1 staged
    s8b a2[8];
    gemm1_repack(sW, bz, b1, lane, h, a2);
    __syncthreads();            // all sW1 reads done
    for (int i = tid; i < 2048; i += 512)
        sW[i] = reinterpret_cast<const s8b*>(Wp2)[i];
    __syncthreads();            // W2 staged
    gemm2_store(sW, a2, b2, lane, h, row0, z);
}

// ---------------- fully fused GIN layer (layers 2..L): hout = MLP(hin + Σ_nbr hin) ----------------
// Gather (wave-private, overlaps W1 staging) -> swapped GEMM1 -> register repack -> GEMM2.
// 32 KB LDS double-use (W1 then W2) -> 4 blocks/CU; __launch_bounds__(512,8) caps VGPR at 64.
__global__ __launch_bounds__(512, 8) void gin_layer(
    const ushort_t* __restrict__ hin, const int* __restrict__ rowptr,
    const int* __restrict__ col,
    const ushort_t* __restrict__ Wp1, const ushort_t* __restrict__ Wp2,
    const float* __restrict__ b1, const float* __restrict__ b2,
    ushort_t* __restrict__ hout, int n)
{
    __shared__ s8b sW[2048];   // 32 KB, reused for W1 then W2

    const int tid = threadIdx.x;
    for (int i = tid; i < 2048; i += 512)
        sW[i] = reinterpret_cast<const s8b*>(Wp1)[i];

    const int lane = tid & 63;
    const int r32  = lane & 31;
    const int h    = lane >> 5;
    const int row0 = blockIdx.x * 256 + (tid >> 6) * 32;
    const int arow = row0 + r32;
    const int koff = h * 8;

    // ---- fused gather: facc = hin[arow] + Σ_nbr hin[col[i]]  (fp32) -> bf16 frags ----
    s8b bz[8];
    {
        float facc[8][8];
        if (arow < n) {
            const ushort_t* hr = hin + (size_t)arow * HD + koff;
#pragma unroll
            for (int ks = 0; ks < 8; ++ks) {
                us8 v = *reinterpret_cast<const us8*>(hr + ks * 16);
#pragma unroll
                for (int e = 0; e < 8; ++e) facc[ks][e] = b2f(v[e]);
            }
            const int lo = rowptr[arow], hi = rowptr[arow + 1];
            for (int i = lo; i < hi; ++i) {
                const ushort_t* hs = hin + (size_t)col[i] * HD + koff;
#pragma unroll
                for (int ks = 0; ks < 8; ++ks) {
                    us8 v = *reinterpret_cast<const us8*>(hs + ks * 16);
#pragma unroll
                    for (int e = 0; e < 8; ++e) facc[ks][e] += b2f(v[e]);
                }
            }
        } else {
#pragma unroll
            for (int ks = 0; ks < 8; ++ks)
#pragma unroll
                for (int e = 0; e < 8; ++e) facc[ks][e] = 0.f;
        }
#pragma unroll
        for (int ks = 0; ks < 8; ++ks)
#pragma unroll
            for (int e = 0; e < 8; ++e) bz[ks][e] = (short)f2b(facc[ks][e]);
    }

    __syncthreads();            // W1 staged (gather overlapped the staging loads)
    s8b a2[8];
    gemm1_repack(sW, bz, b1, lane, h, a2);
    __syncthreads();            // all sW1 reads done
    for (int i = tid; i < 2048; i += 512)
        sW[i] = reinterpret_cast<const s8b*>(Wp2)[i];
    __syncthreads();            // W2 staged
    gemm2_store(sW, a2, b2, lane, h, row0, hout);
}

// ---------------- MFMA GEMM (final projection): out = A[128-blk]@W + b ----------------
template<typename TO, bool RELU>
__global__ __launch_bounds__(256) void gemm_mfma(
    const ushort_t* __restrict__ A, const ushort_t* __restrict__ Wp,
    const float* __restrict__ bias, TO* __restrict__ out, int ldo)
{
    __shared__ s8b sW[2048];    // 32 KB
    const int tid = threadIdx.x;
    for (int i = tid; i < 2048; i += 256)
        sW[i] = reinterpret_cast<const s8b*>(Wp)[i];
    __syncthreads();

    const int lane = tid & 63;
    const int row0 = blockIdx.x * 128 + (tid >> 6) * 32;
    const int arow = row0 + (lane & 31);
    const int koff = (lane >> 5) * 8;

    s8b a[8];
#pragma unroll
    for (int ks = 0; ks < 8; ++ks)
        a[ks] = *reinterpret_cast<const s8b*>(A + (size_t)arow * HD + ks * 16 + koff);

#pragma unroll
    for (int j = 0; j < 4; ++j) {
        f32x16 acc;
#pragma unroll
        for (int i = 0; i < 16; ++i) acc[i] = 0.f;
#pragma unroll
        for (int ks = 0; ks < 8; ++ks)
            acc = __builtin_amdgcn_mfma_f32_32x32x16_bf16(a[ks], sW[(j * 8 + ks) * 64 + lane], acc, 0, 0, 0);
        const int col = j * 32 + (lane & 31);
        const float bv = bias[col];
        const int rbase = row0 + 4 * (lane >> 5);
#pragma unroll
        for (int reg = 0; reg < 16; ++reg) {
            int row = rbase + (reg & 3) + 8 * (reg >> 2);
            float v = acc[reg] + bv;
            if (RELU) v = fmaxf(v, 0.f);
            store1(out + (size_t)row * ldo + col, v);
        }
    }
}

// ---------------- pooling: mean over sorted batch segments ----------------
__global__ __launch_bounds__(128) void pool_kernel(const ushort_t* __restrict__ h,
                                                   const int* __restrict__ batch,
                                                   ushort_t* __restrict__ pooled, int n) {
    int g = blockIdx.x;
    int c = threadIdx.x;   // 128
    int start = lowerb(batch, n, g);
    int end = lowerb(batch, n, g + 1);
    float s = 0.f;
    for (int i = start; i < end; ++i) s += b2f(h[(size_t)i * HD + c]);
    int cnt = end - start; if (cnt < 1) cnt = 1;
    pooled[(size_t)g * HD + c] = f2b(s / (float)cnt);
}

// ---------------- entry ----------------
extern "C" void kernel_launch(void* const* d_in, const int* in_sizes, int n_in,
                              void* d_out, int out_size, void* d_ws, size_t ws_size,
                              hipStream_t stream) {
    const float* x      = (const float*)d_in[0];
    const int*   edge   = (const int*)d_in[1];
    const int*   batch  = (const int*)d_in[2];
    const float* W_enc  = (const float*)d_in[3];
    const float* b_enc  = (const float*)d_in[4];
    const float* W1     = (const float*)d_in[5];
    const float* b1     = (const float*)d_in[6];
    const float* W2     = (const float*)d_in[7];
    const float* b2     = (const float*)d_in[8];
    const float* W_out  = (const float*)d_in[9];
    const float* b_out  = (const float*)d_in[10];

    const int N = in_sizes[0] / 6;
    const int E = in_sizes[1] / 2;
    const int G = out_size / 256;
    const int L = in_sizes[5] / (HD * HD);
    const int Npad = ((N + 255) / 256) * 256;

    const int* srcv = edge;
    const int* dstv = edge + E;

    size_t off = 0;
    auto alloc = [&](size_t bytes) -> char* {
        char* p = (char*)d_ws + off;
        off += (bytes + 255) & ~(size_t)255;
        return p;
    };
    ushort_t* bufA   = (ushort_t*)alloc((size_t)Npad * HD * 2);
    ushort_t* bufB   = (ushort_t*)alloc((size_t)Npad * HD * 2);
    ushort_t* pooled = (ushort_t*)alloc((size_t)G * HD * 2);
    ushort_t* Wp1    = (ushort_t*)alloc((size_t)L * 16384 * 2);
    ushort_t* Wp2    = (ushort_t*)alloc((size_t)L * 16384 * 2);
    ushort_t* WpO    = (ushort_t*)alloc((size_t)2 * 16384 * 2);
    float* xaggb = (float*)alloc((size_t)N * 8 * 4);
    int* rowptr = (int*)alloc((size_t)(N + 1) * 4);
    int* cursor = (int*)alloc((size_t)N * 4);
    int* colidx = (int*)alloc((size_t)E * 4);
    int* deg    = (int*)alloc((size_t)N * 4);
    int* bsum   = (int*)alloc((size_t)1024 * 4);
    (void)ws_size;

    // CSR build (parallel 3-phase scan)
    const int nb = (N + SCAN_CHUNK - 1) / SCAN_CHUNK;
    hipMemsetAsync(deg, 0, (size_t)N * 4, stream);
    hist_kernel<<<(E + 255) / 256, 256, 0, stream>>>(dstv, deg, E);
    scan_a<<<nb, SCAN_NT, 0, stream>>>(deg, bsum, N);
    scan_b<<<1, 1024, 0, stream>>>(bsum, nb);
    scan_c<<<nb, SCAN_NT, 0, stream>>>(deg, bsum, rowptr, cursor, N, E);
    fill_kernel<<<(E + 255) / 256, 256, 0, stream>>>(srcv, dstv, cursor, colidx, E);

    // W pre-pack (bf16 fragment order)
    pack_kernel<<<(L * 2048 + 255) / 256, 256, 0, stream>>>(W1, Wp1, L, HD, HD * HD, 0);
    pack_kernel<<<(L * 2048 + 255) / 256, 256, 0, stream>>>(W2, Wp2, L, HD, HD * HD, 0);
    pack_kernel<<<(2 * 2048 + 255) / 256, 256, 0, stream>>>(W_out, WpO, 2, 256, 0, 128);

    // Layer 1: affine fusion — aggregate 6-dim x, one encoder pass, in-place MLP
    xagg_kernel<<<(N + 255) / 256, 256, 0, stream>>>(x, rowptr, colidx, xaggb, N);
    {
        int threads = ((N + 3) / 4) * 16;
        enc2_kernel<<<(threads + 255) / 256, 256, 0, stream>>>(xaggb, W_enc, b_enc, bufA, N);
    }
    const int nblk = Npad / 256;
    mlp_fused<<<nblk, 512, 0, stream>>>(bufA, Wp1, Wp2, b1, b2);

    // Layers 2..L: fully fused gather+MLP (ping-pong buffers)
    ushort_t* cur = bufA;
    ushort_t* oth = bufB;
    for (int l = 1; l < L; ++l) {
        gin_layer<<<nblk, 512, 0, stream>>>(
            cur, rowptr, colidx,
            Wp1 + (size_t)l * 16384, Wp2 + (size_t)l * 16384,
            b1 + (size_t)l * HD, b2 + (size_t)l * HD, oth, N);
        ushort_t* t = cur; cur = oth; oth = t;
    }

    // pooling
    pool_kernel<<<G, 128, 0, stream>>>(cur, batch, pooled, N);

    // output GEMM: [G,128] @ [128,256] + b_out -> fp32 d_out (two 128-col halves)
    float* outp = (float*)d_out;
    gemm_mfma<float, false><<<G / 128, 256, 0, stream>>>(pooled, WpO, b_out, outp, 256);
    gemm_mfma<float, false><<<G / 128, 256, 0, stream>>>(pooled, WpO + 16384, b_out + 128, outp + 128, 256);
}

// Round 13
// 528.881 us; speedup vs baseline: 4.8346x; 4.8346x over previous
//
#include <hip/hip_runtime.h>

#define HD 128   // hidden dim

typedef unsigned short ushort_t;
typedef __attribute__((ext_vector_type(8))) unsigned short us8;
typedef __attribute__((ext_vector_type(8))) short s8b;       // 8 bf16 = 4 VGPR (MFMA A/B frag)
typedef __attribute__((ext_vector_type(16))) float f32x16;   // MFMA 32x32 accumulator

// ---------------- bf16 <-> f32 ----------------
__device__ __forceinline__ float b2f(unsigned short u) {
    union { unsigned int i; float f; } v; v.i = ((unsigned int)u) << 16; return v.f;
}
__device__ __forceinline__ unsigned short f2b(float f) {
    union { float f; unsigned int i; } v; v.f = f;
    unsigned int u = v.i;
    return (unsigned short)((u + 0x7fffu + ((u >> 16) & 1u)) >> 16);  // RNE
}

__device__ __forceinline__ void load8f(const float* p, float* o) {
    float4 a = *reinterpret_cast<const float4*>(p);
    float4 b = *reinterpret_cast<const float4*>(p + 4);
    o[0]=a.x;o[1]=a.y;o[2]=a.z;o[3]=a.w;o[4]=b.x;o[5]=b.y;o[6]=b.z;o[7]=b.w;
}
__device__ __forceinline__ void load8b(const ushort_t* p, float* o) {
    us8 v = *reinterpret_cast<const us8*>(p);
#pragma unroll
    for (int j = 0; j < 8; ++j) o[j] = b2f(v[j]);
}
__device__ __forceinline__ void store8b(ushort_t* p, const float* s) {
    us8 v;
#pragma unroll
    for (int j = 0; j < 8; ++j) v[j] = f2b(s[j]);
    *reinterpret_cast<us8*>(p) = v;
}

__device__ __forceinline__ void store1(float* p, float v) { *p = v; }
__device__ __forceinline__ void store1(ushort_t* p, float v) { *p = f2b(v); }

__device__ __forceinline__ int lowerb(const int* __restrict__ a, int n, int v) {
    int lo = 0, hi = n;
    while (lo < hi) { int m = (lo + hi) >> 1; if (a[m] < v) lo = m + 1; else hi = m; }
    return lo;
}

// ---------------- CSR build ----------------
__global__ void hist_kernel(const int* __restrict__ dst, int* __restrict__ deg, int e) {
    int i = blockIdx.x * blockDim.x + threadIdx.x;
    if (i < e) atomicAdd(&deg[dst[i]], 1);
}

#define SCAN_NT 256
#define SCAN_BPT 8
#define SCAN_CHUNK (SCAN_NT * SCAN_BPT)   // 2048

__global__ __launch_bounds__(SCAN_NT) void scan_a(const int* __restrict__ deg,
                                                  int* __restrict__ bsum, int n) {
    int tid = threadIdx.x;
    int base = blockIdx.x * SCAN_CHUNK + tid * SCAN_BPT;
    int sum = 0;
    if (base + SCAN_BPT <= n) {
        int4 v0 = *reinterpret_cast<const int4*>(deg + base);
        int4 v1 = *reinterpret_cast<const int4*>(deg + base + 4);
        sum = v0.x + v0.y + v0.z + v0.w + v1.x + v1.y + v1.z + v1.w;
    } else {
        for (int j = 0; j < SCAN_BPT; ++j) { int i = base + j; if (i < n) sum += deg[i]; }
    }
    __shared__ int sd[SCAN_NT];
    sd[tid] = sum; __syncthreads();
    for (int off = SCAN_NT / 2; off > 0; off >>= 1) {
        if (tid < off) sd[tid] += sd[tid + off];
        __syncthreads();
    }
    if (tid == 0) bsum[blockIdx.x] = sd[0];
}

__global__ __launch_bounds__(1024) void scan_b(int* __restrict__ bsum, int nb) {
    __shared__ int ps[1024];
    int tid = threadIdx.x;
    int v = (tid < nb) ? bsum[tid] : 0;
    ps[tid] = v; __syncthreads();
    for (int off = 1; off < 1024; off <<= 1) {
        int t = (tid >= off) ? ps[tid - off] : 0;
        __syncthreads();
        ps[tid] += t;
        __syncthreads();
    }
    if (tid < nb) bsum[tid] = ps[tid] - v;   // exclusive block offsets
}

__global__ __launch_bounds__(SCAN_NT) void scan_c(const int* __restrict__ deg,
                                                  const int* __restrict__ bsum,
                                                  int* __restrict__ rowptr,
                                                  int* __restrict__ cursor,
                                                  int n, int etot) {
    int tid = threadIdx.x;
    int base = blockIdx.x * SCAN_CHUNK + tid * SCAN_BPT;
    int vals[SCAN_BPT];
    if (base + SCAN_BPT <= n) {
        int4 v0 = *reinterpret_cast<const int4*>(deg + base);
        int4 v1 = *reinterpret_cast<const int4*>(deg + base + 4);
        vals[0]=v0.x; vals[1]=v0.y; vals[2]=v0.z; vals[3]=v0.w;
        vals[4]=v1.x; vals[5]=v1.y; vals[6]=v1.z; vals[7]=v1.w;
    } else {
        for (int j = 0; j < SCAN_BPT; ++j) { int i = base + j; vals[j] = (i < n) ? deg[i] : 0; }
    }
    int sum = 0;
#pragma unroll
    for (int j = 0; j < SCAN_BPT; ++j) sum += vals[j];
    __shared__ int ps[SCAN_NT];
    ps[tid] = sum; __syncthreads();
    for (int off = 1; off < SCAN_NT; off <<= 1) {
        int t = (tid >= off) ? ps[tid - off] : 0;
        __syncthreads();
        ps[tid] += t;
        __syncthreads();
    }
    int run = bsum[blockIdx.x] + ps[tid] - sum;
#pragma unroll
    for (int j = 0; j < SCAN_BPT; ++j) {
        int i = base + j;
        if (i < n) { rowptr[i] = run; cursor[i] = run; run += vals[j]; }
    }
    if (blockIdx.x == 0 && tid == 0) rowptr[n] = etot;
}

__global__ void fill_kernel(const int* __restrict__ src, const int* __restrict__ dst,
                            int* __restrict__ cursor, int* __restrict__ col, int e) {
    int i = blockIdx.x * blockDim.x + threadIdx.x;
    if (i < e) { int slot = atomicAdd(&cursor[dst[i]], 1); col[slot] = src[i]; }
}

// ---------------- W pre-pack into MFMA B-fragment order (bf16) ----------------
// flat idx = ((mat*4 + j)*8 + ks)*64 + lane; elem e = W[ks*16+(lane>>5)*8+e][mat*col_off + j*32 + (lane&31)]
// NOTE: B-frag(W) is bit-identical to A-frag(W^T) — used by the swapped GEMM1.
__global__ void pack_kernel(const float* __restrict__ W, ushort_t* __restrict__ Wp,
                            int nmat, int ld, int mat_stride, int col_off) {
    int idx = blockIdx.x * blockDim.x + threadIdx.x;
    if (idx >= nmat * 2048) return;
    int lane = idx & 63;
    int ks = (idx >> 6) & 7;
    int j = (idx >> 9) & 3;
    int mat = idx >> 11;
    const float* Wm = W + (size_t)mat * mat_stride;
    int k0 = ks * 16 + (lane >> 5) * 8;
    int n = mat * col_off + j * 32 + (lane & 31);
    us8 o;
#pragma unroll
    for (int e = 0; e < 8; ++e) o[e] = f2b(Wm[(size_t)(k0 + e) * ld + n]);
    *reinterpret_cast<us8*>(Wp + (size_t)idx * 8) = o;
}

// ---------------- fused x-aggregation: xa[node] = {x[node] + Σ_nbr x[nbr], 1+deg} ----------------
__global__ void xagg_kernel(const float* __restrict__ x, const int* __restrict__ rowptr,
                            const int* __restrict__ col, float* __restrict__ xa, int n) {
    int node = blockIdx.x * blockDim.x + threadIdx.x;
    if (node >= n) return;
    const float2* xr = reinterpret_cast<const float2*>(x + (size_t)node * 6);
    float2 a0 = xr[0], a1 = xr[1], a2 = xr[2];
    int lo = rowptr[node], hi = rowptr[node + 1];
    for (int i = lo; i < hi; ++i) {
        const float2* xs = reinterpret_cast<const float2*>(x + (size_t)col[i] * 6);
        float2 s0 = xs[0], s1 = xs[1], s2 = xs[2];
        a0.x += s0.x; a0.y += s0.y; a1.x += s1.x; a1.y += s1.y; a2.x += s2.x; a2.y += s2.y;
    }
    float cnt = (float)(1 + hi - lo);
    float4 o0; o0.x = a0.x; o0.y = a0.y; o0.z = a1.x; o0.w = a1.y;
    float4 o1; o1.x = a2.x; o1.y = a2.y; o1.z = cnt; o1.w = 0.f;
    reinterpret_cast<float4*>(xa + (size_t)node * 8)[0] = o0;
    reinterpret_cast<float4*>(xa + (size_t)node * 8)[1] = o1;
}

// ---------------- encoder v2: z1 = xa[:, :6] @ W_enc + xa[:,6]·b_enc  (bf16 out) ----------------
__global__ void enc2_kernel(const float* __restrict__ xa, const float* __restrict__ W,
                            const float* __restrict__ b, ushort_t* __restrict__ z, int n) {
    int t = blockIdx.x * blockDim.x + threadIdx.x;
    int q = t >> 4, g = t & 15;
    int node0 = q * 4;
    if (node0 >= n) return;
    float w[6][8];
#pragma unroll
    for (int d = 0; d < 6; ++d) load8f(W + d * HD + g * 8, w[d]);
    float bias[8];
    load8f(b + g * 8, bias);
#pragma unroll
    for (int u = 0; u < 4; ++u) {
        int node = node0 + u;
        if (node >= n) break;
        float4 a0 = reinterpret_cast<const float4*>(xa + (size_t)node * 8)[0];
        float4 a1 = reinterpret_cast<const float4*>(xa + (size_t)node * 8)[1];
        float xv[6] = {a0.x, a0.y, a0.z, a0.w, a1.x, a1.y};
        float cnt = a1.z;
        float acc[8];
#pragma unroll
        for (int j = 0; j < 8; ++j) acc[j] = cnt * bias[j];
#pragma unroll
        for (int d = 0; d < 6; ++d)
#pragma unroll
            for (int j = 0; j < 8; ++j) acc[j] += xv[d] * w[d][j];
        store8b(z + (size_t)node * HD + g * 8, acc);
    }
}

// ---------------- GEMM1(swapped)+repack and GEMM2 helpers (shared by mlp/gin kernels) ----------------
__device__ __forceinline__ void gemm1_repack(const s8b* __restrict__ sW, const s8b* bz,
                                             const float* __restrict__ b1,
                                             int lane, int h, s8b* a2) {
#pragma unroll
    for (int j = 0; j < 4; ++j) {
        f32x16 c;
#pragma unroll
        for (int i = 0; i < 16; ++i) c[i] = 0.f;
#pragma unroll
        for (int ks = 0; ks < 8; ++ks)
            c = __builtin_amdgcn_mfma_f32_32x32x16_bf16(sW[(j * 8 + ks) * 64 + lane], bz[ks], c, 0, 0, 0);
        unsigned int w[4][2];
#pragma unroll
        for (int b = 0; b < 4; ++b) {
            float4 bv = *reinterpret_cast<const float4*>(b1 + j * 32 + b * 8 + 4 * h);
            float v0 = fmaxf(c[4 * b + 0] + bv.x, 0.f);
            float v1 = fmaxf(c[4 * b + 1] + bv.y, 0.f);
            float v2 = fmaxf(c[4 * b + 2] + bv.z, 0.f);
            float v3 = fmaxf(c[4 * b + 3] + bv.w, 0.f);
            w[b][0] = (unsigned int)f2b(v0) | ((unsigned int)f2b(v1) << 16);
            w[b][1] = (unsigned int)f2b(v2) | ((unsigned int)f2b(v3) << 16);
        }
        unsigned int p[4][2];
#pragma unroll
        for (int b = 0; b < 4; ++b) {
            p[b][0] = (unsigned int)__shfl_xor((int)w[b][0], 32);
            p[b][1] = (unsigned int)__shfl_xor((int)w[b][1], 32);
        }
        union { unsigned int u[4]; s8b v; } t0, t1;
        t0.u[0] = (h == 0) ? w[0][0] : p[1][0];
        t0.u[1] = (h == 0) ? w[0][1] : p[1][1];
        t0.u[2] = (h == 0) ? p[0][0] : w[1][0];
        t0.u[3] = (h == 0) ? p[0][1] : w[1][1];
        t1.u[0] = (h == 0) ? w[2][0] : p[3][0];
        t1.u[1] = (h == 0) ? w[2][1] : p[3][1];
        t1.u[2] = (h == 0) ? p[2][0] : w[3][0];
        t1.u[3] = (h == 0) ? p[2][1] : w[3][1];
        a2[2 * j]     = t0.v;
        a2[2 * j + 1] = t1.v;
    }
}

__device__ __forceinline__ void gemm2_store(const s8b* __restrict__ sW, const s8b* a2,
                                            const float* __restrict__ b2,
                                            int lane, int h, int row0,
                                            ushort_t* __restrict__ out) {
    const int r32 = lane & 31;
#pragma unroll
    for (int j = 0; j < 4; ++j) {
        f32x16 c;
#pragma unroll
        for (int i = 0; i < 16; ++i) c[i] = 0.f;
#pragma unroll
        for (int ks = 0; ks < 8; ++ks)
            c = __builtin_amdgcn_mfma_f32_32x32x16_bf16(a2[ks], sW[(j * 8 + ks) * 64 + lane], c, 0, 0, 0);
        const int ccol = j * 32 + r32;
        const float bv = b2[ccol];
        const int rbase = row0 + 4 * h;
#pragma unroll
        for (int reg = 0; reg < 16; ++reg) {
            int row = rbase + (reg & 3) + 8 * (reg >> 2);
            out[(size_t)row * HD + ccol] = f2b(fmaxf(c[reg] + bv, 0.f));
        }
    }
}

// ---------------- fused GIN MLP (layer 1): z <- relu(relu(z@W1+b1)@W2+b2)  IN-PLACE ----------------
// 32 KB LDS, W1 then W2 staged into the SAME buffer. __launch_bounds__(512,4): cap 128 VGPR
// (compiler lands ~60 — round-11 evidence; (512,8)'s 64-cap caused scratch spills, round 12).
__global__ __launch_bounds__(512, 4) void mlp_fused(
    ushort_t* __restrict__ z,
    const ushort_t* __restrict__ Wp1, const ushort_t* __restrict__ Wp2,
    const float* __restrict__ b1, const float* __restrict__ b2)
{
    __shared__ s8b sW[2048];   // 32 KB, reused for W1 then W2

    const int tid = threadIdx.x;
    for (int i = tid; i < 2048; i += 512)
        sW[i] = reinterpret_cast<const s8b*>(Wp1)[i];

    const int lane = tid & 63;
    const int r32  = lane & 31;
    const int h    = lane >> 5;
    const int row0 = blockIdx.x * 256 + (tid >> 6) * 32;
    const int arow = row0 + r32;
    const int koff = h * 8;

    s8b bz[8];
#pragma unroll
    for (int ks = 0; ks < 8; ++ks)
        bz[ks] = *reinterpret_cast<const s8b*>(z + (size_t)arow * HD + ks * 16 + koff);

    __syncthreads();            // W1 staged
    s8b a2[8];
    gemm1_repack(sW, bz, b1, lane, h, a2);
    __syncthreads();            // all sW1 reads done
    for (int i = tid; i < 2048; i += 512)
        sW[i] = reinterpret_cast<const s8b*>(Wp2)[i];
    __syncthreads();            // W2 staged
    gemm2_store(sW, a2, b2, lane, h, row0, z);
}

// ---------------- fully fused GIN layer (layers 2..L): hout = MLP(hin + Σ_nbr hin) ----------------
// Gather (wave-private, overlaps W1 staging) -> swapped GEMM1 -> register repack -> GEMM2.
// 32 KB LDS double-use (W1 then W2); (512,4) bound — generous VGPR cap, no spills.
__global__ __launch_bounds__(512, 4) void gin_layer(
    const ushort_t* __restrict__ hin, const int* __restrict__ rowptr,
    const int* __restrict__ col,
    const ushort_t* __restrict__ Wp1, const ushort_t* __restrict__ Wp2,
    const float* __restrict__ b1, const float* __restrict__ b2,
    ushort_t* __restrict__ hout, int n)
{
    __shared__ s8b sW[2048];   // 32 KB, reused for W1 then W2

    const int tid = threadIdx.x;
    for (int i = tid; i < 2048; i += 512)
        sW[i] = reinterpret_cast<const s8b*>(Wp1)[i];

    const int lane = tid & 63;
    const int r32  = lane & 31;
    const int h    = lane >> 5;
    const int row0 = blockIdx.x * 256 + (tid >> 6) * 32;
    const int arow = row0 + r32;
    const int koff = h * 8;

    // ---- fused gather: facc = hin[arow] + Σ_nbr hin[col[i]]  (fp32) -> bf16 frags ----
    s8b bz[8];
    {
        float facc[8][8];
        if (arow < n) {
            const ushort_t* hr = hin + (size_t)arow * HD + koff;
#pragma unroll
            for (int ks = 0; ks < 8; ++ks) {
                us8 v = *reinterpret_cast<const us8*>(hr + ks * 16);
#pragma unroll
                for (int e = 0; e < 8; ++e) facc[ks][e] = b2f(v[e]);
            }
            const int lo = rowptr[arow], hi = rowptr[arow + 1];
            for (int i = lo; i < hi; ++i) {
                const ushort_t* hs = hin + (size_t)col[i] * HD + koff;
#pragma unroll
                for (int ks = 0; ks < 8; ++ks) {
                    us8 v = *reinterpret_cast<const us8*>(hs + ks * 16);
#pragma unroll
                    for (int e = 0; e < 8; ++e) facc[ks][e] += b2f(v[e]);
                }
            }
        } else {
#pragma unroll
            for (int ks = 0; ks < 8; ++ks)
#pragma unroll
                for (int e = 0; e < 8; ++e) facc[ks][e] = 0.f;
        }
#pragma unroll
        for (int ks = 0; ks < 8; ++ks)
#pragma unroll
            for (int e = 0; e < 8; ++e) bz[ks][e] = (short)f2b(facc[ks][e]);
    }

    __syncthreads();            // W1 staged (gather overlapped the staging loads)
    s8b a2[8];
    gemm1_repack(sW, bz, b1, lane, h, a2);
    __syncthreads();            // all sW1 reads done
    for (int i = tid; i < 2048; i += 512)
        sW[i] = reinterpret_cast<const s8b*>(Wp2)[i];
    __syncthreads();            // W2 staged
    gemm2_store(sW, a2, b2, lane, h, row0, hout);
}

// ---------------- MFMA GEMM (final projection): out = A[128-blk]@W + b ----------------
template<typename TO, bool RELU>
__global__ __launch_bounds__(256) void gemm_mfma(
    const ushort_t* __restrict__ A, const ushort_t* __restrict__ Wp,
    const float* __restrict__ bias, TO* __restrict__ out, int ldo)
{
    __shared__ s8b sW[2048];    // 32 KB
    const int tid = threadIdx.x;
    for (int i = tid; i < 2048; i += 256)
        sW[i] = reinterpret_cast<const s8b*>(Wp)[i];
    __syncthreads();

    const int lane = tid & 63;
    const int row0 = blockIdx.x * 128 + (tid >> 6) * 32;
    const int arow = row0 + (lane & 31);
    const int koff = (lane >> 5) * 8;

    s8b a[8];
#pragma unroll
    for (int ks = 0; ks < 8; ++ks)
        a[ks] = *reinterpret_cast<const s8b*>(A + (size_t)arow * HD + ks * 16 + koff);

#pragma unroll
    for (int j = 0; j < 4; ++j) {
        f32x16 acc;
#pragma unroll
        for (int i = 0; i < 16; ++i) acc[i] = 0.f;
#pragma unroll
        for (int ks = 0; ks < 8; ++ks)
            acc = __builtin_amdgcn_mfma_f32_32x32x16_bf16(a[ks], sW[(j * 8 + ks) * 64 + lane], acc, 0, 0, 0);
        const int col = j * 32 + (lane & 31);
        const float bv = bias[col];
        const int rbase = row0 + 4 * (lane >> 5);
#pragma unroll
        for (int reg = 0; reg < 16; ++reg) {
            int row = rbase + (reg & 3) + 8 * (reg >> 2);
            float v = acc[reg] + bv;
            if (RELU) v = fmaxf(v, 0.f);
            store1(out + (size_t)row * ldo + col, v);
        }
    }
}

// ---------------- pooling: mean over sorted batch segments ----------------
__global__ __launch_bounds__(128) void pool_kernel(const ushort_t* __restrict__ h,
                                                   const int* __restrict__ batch,
                                                   ushort_t* __restrict__ pooled, int n) {
    int g = blockIdx.x;
    int c = threadIdx.x;   // 128
    int start = lowerb(batch, n, g);
    int end = lowerb(batch, n, g + 1);
    float s = 0.f;
    for (int i = start; i < end; ++i) s += b2f(h[(size_t)i * HD + c]);
    int cnt = end - start; if (cnt < 1) cnt = 1;
    pooled[(size_t)g * HD + c] = f2b(s / (float)cnt);
}

// ---------------- entry ----------------
extern "C" void kernel_launch(void* const* d_in, const int* in_sizes, int n_in,
                              void* d_out, int out_size, void* d_ws, size_t ws_size,
                              hipStream_t stream) {
    const float* x      = (const float*)d_in[0];
    const int*   edge   = (const int*)d_in[1];
    const int*   batch  = (const int*)d_in[2];
    const float* W_enc  = (const float*)d_in[3];
    const float* b_enc  = (const float*)d_in[4];
    const float* W1     = (const float*)d_in[5];
    const float* b1     = (const float*)d_in[6];
    const float* W2     = (const float*)d_in[7];
    const float* b2     = (const float*)d_in[8];
    const float* W_out  = (const float*)d_in[9];
    const float* b_out  = (const float*)d_in[10];

    const int N = in_sizes[0] / 6;
    const int E = in_sizes[1] / 2;
    const int G = out_size / 256;
    const int L = in_sizes[5] / (HD * HD);
    const int Npad = ((N + 255) / 256) * 256;

    const int* srcv = edge;
    const int* dstv = edge + E;

    size_t off = 0;
    auto alloc = [&](size_t bytes) -> char* {
        char* p = (char*)d_ws + off;
        off += (bytes + 255) & ~(size_t)255;
        return p;
    };
    ushort_t* bufA   = (ushort_t*)alloc((size_t)Npad * HD * 2);
    ushort_t* bufB   = (ushort_t*)alloc((size_t)Npad * HD * 2);
    ushort_t* pooled = (ushort_t*)alloc((size_t)G * HD * 2);
    ushort_t* Wp1    = (ushort_t*)alloc((size_t)L * 16384 * 2);
    ushort_t* Wp2    = (ushort_t*)alloc((size_t)L * 16384 * 2);
    ushort_t* WpO    = (ushort_t*)alloc((size_t)2 * 16384 * 2);
    float* xaggb = (float*)alloc((size_t)N * 8 * 4);
    int* rowptr = (int*)alloc((size_t)(N + 1) * 4);
    int* cursor = (int*)alloc((size_t)N * 4);
    int* colidx = (int*)alloc((size_t)E * 4);
    int* deg    = (int*)alloc((size_t)N * 4);
    int* bsum   = (int*)alloc((size_t)1024 * 4);
    (void)ws_size;

    // CSR build (parallel 3-phase scan)
    const int nb = (N + SCAN_CHUNK - 1) / SCAN_CHUNK;
    hipMemsetAsync(deg, 0, (size_t)N * 4, stream);
    hist_kernel<<<(E + 255) / 256, 256, 0, stream>>>(dstv, deg, E);
    scan_a<<<nb, SCAN_NT, 0, stream>>>(deg, bsum, N);
    scan_b<<<1, 1024, 0, stream>>>(bsum, nb);
    scan_c<<<nb, SCAN_NT, 0, stream>>>(deg, bsum, rowptr, cursor, N, E);
    fill_kernel<<<(E + 255) / 256, 256, 0, stream>>>(srcv, dstv, cursor, colidx, E);

    // W pre-pack (bf16 fragment order)
    pack_kernel<<<(L * 2048 + 255) / 256, 256, 0, stream>>>(W1, Wp1, L, HD, HD * HD, 0);
    pack_kernel<<<(L * 2048 + 255) / 256, 256, 0, stream>>>(W2, Wp2, L, HD, HD * HD, 0);
    pack_kernel<<<(2 * 2048 + 255) / 256, 256, 0, stream>>>(W_out, WpO, 2, 256, 0, 128);

    // Layer 1: affine fusion — aggregate 6-dim x, one encoder pass, in-place MLP
    xagg_kernel<<<(N + 255) / 256, 256, 0, stream>>>(x, rowptr, colidx, xaggb, N);
    {
        int threads = ((N + 3) / 4) * 16;
        enc2_kernel<<<(threads + 255) / 256, 256, 0, stream>>>(xaggb, W_enc, b_enc, bufA, N);
    }
    const int nblk = Npad / 256;
    mlp_fused<<<nblk, 512, 0, stream>>>(bufA, Wp1, Wp2, b1, b2);

    // Layers 2..L: fully fused gather+MLP (ping-pong buffers)
    ushort_t* cur = bufA;
    ushort_t* oth = bufB;
    for (int l = 1; l < L; ++l) {
        gin_layer<<<nblk, 512, 0, stream>>>(
            cur, rowptr, colidx,
            Wp1 + (size_t)l * 16384, Wp2 + (size_t)l * 16384,
            b1 + (size_t)l * HD, b2 + (size_t)l * HD, oth, N);
        ushort_t* t = cur; cur = oth; oth = t;
    }

    // pooling
    pool_kernel<<<G, 128, 0, stream>>>(cur, batch, pooled, N);

    // output GEMM: [G,128] @ [128,256] + b_out -> fp32 d_out (two 128-col halves)
    float* outp = (float*)d_out;
    gemm_mfma<float, false><<<G / 128, 256, 0, stream>>>(pooled, WpO, b_out, outp, 256);
    gemm_mfma<float, false><<<G / 128, 256, 0, stream>>>(pooled, WpO + 16384, b_out + 128, outp + 128, 256);
}

// Round 14
// 499.942 us; speedup vs baseline: 5.1144x; 1.0579x over previous
//
#include <hip/hip_runtime.h>

#define HD 128   // hidden dim

typedef unsigned short ushort_t;
typedef __attribute__((ext_vector_type(8))) unsigned short us8;
typedef __attribute__((ext_vector_type(8))) short s8b;       // 8 bf16 = 4 VGPR (MFMA A/B frag)
typedef __attribute__((ext_vector_type(16))) float f32x16;   // MFMA 32x32 accumulator

// ---------------- bf16 <-> f32 ----------------
__device__ __forceinline__ float b2f(unsigned short u) {
    union { unsigned int i; float f; } v; v.i = ((unsigned int)u) << 16; return v.f;
}
__device__ __forceinline__ unsigned short f2b(float f) {
    union { float f; unsigned int i; } v; v.f = f;
    unsigned int u = v.i;
    return (unsigned short)((u + 0x7fffu + ((u >> 16) & 1u)) >> 16);  // RNE
}

__device__ __forceinline__ void load8f(const float* p, float* o) {
    float4 a = *reinterpret_cast<const float4*>(p);
    float4 b = *reinterpret_cast<const float4*>(p + 4);
    o[0]=a.x;o[1]=a.y;o[2]=a.z;o[3]=a.w;o[4]=b.x;o[5]=b.y;o[6]=b.z;o[7]=b.w;
}
__device__ __forceinline__ void load8b(const ushort_t* p, float* o) {
    us8 v = *reinterpret_cast<const us8*>(p);
#pragma unroll
    for (int j = 0; j < 8; ++j) o[j] = b2f(v[j]);
}
__device__ __forceinline__ void store8b(ushort_t* p, const float* s) {
    us8 v;
#pragma unroll
    for (int j = 0; j < 8; ++j) v[j] = f2b(s[j]);
    *reinterpret_cast<us8*>(p) = v;
}

__device__ __forceinline__ void store1(float* p, float v) { *p = v; }
__device__ __forceinline__ void store1(ushort_t* p, float v) { *p = f2b(v); }

__device__ __forceinline__ int lowerb(const int* __restrict__ a, int n, int v) {
    int lo = 0, hi = n;
    while (lo < hi) { int m = (lo + hi) >> 1; if (a[m] < v) lo = m + 1; else hi = m; }
    return lo;
}

// ---------------- CSR build ----------------
__global__ void hist_kernel(const int* __restrict__ dst, int* __restrict__ deg, int e) {
    int i = blockIdx.x * blockDim.x + threadIdx.x;
    if (i < e) atomicAdd(&deg[dst[i]], 1);
}

#define SCAN_NT 256
#define SCAN_BPT 8
#define SCAN_CHUNK (SCAN_NT * SCAN_BPT)   // 2048

__global__ __launch_bounds__(SCAN_NT) void scan_a(const int* __restrict__ deg,
                                                  int* __restrict__ bsum, int n) {
    int tid = threadIdx.x;
    int base = blockIdx.x * SCAN_CHUNK + tid * SCAN_BPT;
    int sum = 0;
    if (base + SCAN_BPT <= n) {
        int4 v0 = *reinterpret_cast<const int4*>(deg + base);
        int4 v1 = *reinterpret_cast<const int4*>(deg + base + 4);
        sum = v0.x + v0.y + v0.z + v0.w + v1.x + v1.y + v1.z + v1.w;
    } else {
        for (int j = 0; j < SCAN_BPT; ++j) { int i = base + j; if (i < n) sum += deg[i]; }
    }
    __shared__ int sd[SCAN_NT];
    sd[tid] = sum; __syncthreads();
    for (int off = SCAN_NT / 2; off > 0; off >>= 1) {
        if (tid < off) sd[tid] += sd[tid + off];
        __syncthreads();
    }
    if (tid == 0) bsum[blockIdx.x] = sd[0];
}

__global__ __launch_bounds__(1024) void scan_b(int* __restrict__ bsum, int nb) {
    __shared__ int ps[1024];
    int tid = threadIdx.x;
    int v = (tid < nb) ? bsum[tid] : 0;
    ps[tid] = v; __syncthreads();
    for (int off = 1; off < 1024; off <<= 1) {
        int t = (tid >= off) ? ps[tid - off] : 0;
        __syncthreads();
        ps[tid] += t;
        __syncthreads();
    }
    if (tid < nb) bsum[tid] = ps[tid] - v;   // exclusive block offsets
}

__global__ __launch_bounds__(SCAN_NT) void scan_c(const int* __restrict__ deg,
                                                  const int* __restrict__ bsum,
                                                  int* __restrict__ rowptr,
                                                  int* __restrict__ cursor,
                                                  int n, int etot) {
    int tid = threadIdx.x;
    int base = blockIdx.x * SCAN_CHUNK + tid * SCAN_BPT;
    int vals[SCAN_BPT];
    if (base + SCAN_BPT <= n) {
        int4 v0 = *reinterpret_cast<const int4*>(deg + base);
        int4 v1 = *reinterpret_cast<const int4*>(deg + base + 4);
        vals[0]=v0.x; vals[1]=v0.y; vals[2]=v0.z; vals[3]=v0.w;
        vals[4]=v1.x; vals[5]=v1.y; vals[6]=v1.z; vals[7]=v1.w;
    } else {
        for (int j = 0; j < SCAN_BPT; ++j) { int i = base + j; vals[j] = (i < n) ? deg[i] : 0; }
    }
    int sum = 0;
#pragma unroll
    for (int j = 0; j < SCAN_BPT; ++j) sum += vals[j];
    __shared__ int ps[SCAN_NT];
    ps[tid] = sum; __syncthreads();
    for (int off = 1; off < SCAN_NT; off <<= 1) {
        int t = (tid >= off) ? ps[tid - off] : 0;
        __syncthreads();
        ps[tid] += t;
        __syncthreads();
    }
    int run = bsum[blockIdx.x] + ps[tid] - sum;
#pragma unroll
    for (int j = 0; j < SCAN_BPT; ++j) {
        int i = base + j;
        if (i < n) { rowptr[i] = run; cursor[i] = run; run += vals[j]; }
    }
    if (blockIdx.x == 0 && tid == 0) rowptr[n] = etot;
}

__global__ void fill_kernel(const int* __restrict__ src, const int* __restrict__ dst,
                            int* __restrict__ cursor, int* __restrict__ col, int e) {
    int i = blockIdx.x * blockDim.x + threadIdx.x;
    if (i < e) { int slot = atomicAdd(&cursor[dst[i]], 1); col[slot] = src[i]; }
}

// ---------------- W pre-pack into MFMA B-fragment order (bf16) ----------------
// flat idx = ((mat*4 + j)*8 + ks)*64 + lane; elem e = W[ks*16+(lane>>5)*8+e][mat*col_off + j*32 + (lane&31)]
// NOTE: B-frag(W) is bit-identical to A-frag(W^T) — used by the swapped GEMM1.
__global__ void pack_kernel(const float* __restrict__ W, ushort_t* __restrict__ Wp,
                            int nmat, int ld, int mat_stride, int col_off) {
    int idx = blockIdx.x * blockDim.x + threadIdx.x;
    if (idx >= nmat * 2048) return;
    int lane = idx & 63;
    int ks = (idx >> 6) & 7;
    int j = (idx >> 9) & 3;
    int mat = idx >> 11;
    const float* Wm = W + (size_t)mat * mat_stride;
    int k0 = ks * 16 + (lane >> 5) * 8;
    int n = mat * col_off + j * 32 + (lane & 31);
    us8 o;
#pragma unroll
    for (int e = 0; e < 8; ++e) o[e] = f2b(Wm[(size_t)(k0 + e) * ld + n]);
    *reinterpret_cast<us8*>(Wp + (size_t)idx * 8) = o;
}

// ---------------- fused x-aggregation: xa[node] = {x[node] + Σ_nbr x[nbr], 1+deg} ----------------
__global__ void xagg_kernel(const float* __restrict__ x, const int* __restrict__ rowptr,
                            const int* __restrict__ col, float* __restrict__ xa, int n) {
    int node = blockIdx.x * blockDim.x + threadIdx.x;
    if (node >= n) return;
    const float2* xr = reinterpret_cast<const float2*>(x + (size_t)node * 6);
    float2 a0 = xr[0], a1 = xr[1], a2 = xr[2];
    int lo = rowptr[node], hi = rowptr[node + 1];
    for (int i = lo; i < hi; ++i) {
        const float2* xs = reinterpret_cast<const float2*>(x + (size_t)col[i] * 6);
        float2 s0 = xs[0], s1 = xs[1], s2 = xs[2];
        a0.x += s0.x; a0.y += s0.y; a1.x += s1.x; a1.y += s1.y; a2.x += s2.x; a2.y += s2.y;
    }
    float cnt = (float)(1 + hi - lo);
    float4 o0; o0.x = a0.x; o0.y = a0.y; o0.z = a1.x; o0.w = a1.y;
    float4 o1; o1.x = a2.x; o1.y = a2.y; o1.z = cnt; o1.w = 0.f;
    reinterpret_cast<float4*>(xa + (size_t)node * 8)[0] = o0;
    reinterpret_cast<float4*>(xa + (size_t)node * 8)[1] = o1;
}

// ---------------- encoder v2: z1 = xa[:, :6] @ W_enc + xa[:,6]·b_enc  (bf16 out) ----------------
__global__ void enc2_kernel(const float* __restrict__ xa, const float* __restrict__ W,
                            const float* __restrict__ b, ushort_t* __restrict__ z, int n) {
    int t = blockIdx.x * blockDim.x + threadIdx.x;
    int q = t >> 4, g = t & 15;
    int node0 = q * 4;
    if (node0 >= n) return;
    float w[6][8];
#pragma unroll
    for (int d = 0; d < 6; ++d) load8f(W + d * HD + g * 8, w[d]);
    float bias[8];
    load8f(b + g * 8, bias);
#pragma unroll
    for (int u = 0; u < 4; ++u) {
        int node = node0 + u;
        if (node >= n) break;
        float4 a0 = reinterpret_cast<const float4*>(xa + (size_t)node * 8)[0];
        float4 a1 = reinterpret_cast<const float4*>(xa + (size_t)node * 8)[1];
        float xv[6] = {a0.x, a0.y, a0.z, a0.w, a1.x, a1.y};
        float cnt = a1.z;
        float acc[8];
#pragma unroll
        for (int j = 0; j < 8; ++j) acc[j] = cnt * bias[j];
#pragma unroll
        for (int d = 0; d < 6; ++d)
#pragma unroll
            for (int j = 0; j < 8; ++j) acc[j] += xv[d] * w[d][j];
        store8b(z + (size_t)node * HD + g * 8, acc);
    }
}

// ---------------- GEMM1(swapped)+repack and GEMM2 helpers (shared by mlp/gin kernels) ----------------
__device__ __forceinline__ void gemm1_repack(const s8b* __restrict__ sW, const s8b* bz,
                                             const float* __restrict__ b1,
                                             int lane, int h, s8b* a2) {
#pragma unroll
    for (int j = 0; j < 4; ++j) {
        f32x16 c;
#pragma unroll
        for (int i = 0; i < 16; ++i) c[i] = 0.f;
#pragma unroll
        for (int ks = 0; ks < 8; ++ks)
            c = __builtin_amdgcn_mfma_f32_32x32x16_bf16(sW[(j * 8 + ks) * 64 + lane], bz[ks], c, 0, 0, 0);
        unsigned int w[4][2];
#pragma unroll
        for (int b = 0; b < 4; ++b) {
            float4 bv = *reinterpret_cast<const float4*>(b1 + j * 32 + b * 8 + 4 * h);
            float v0 = fmaxf(c[4 * b + 0] + bv.x, 0.f);
            float v1 = fmaxf(c[4 * b + 1] + bv.y, 0.f);
            float v2 = fmaxf(c[4 * b + 2] + bv.z, 0.f);
            float v3 = fmaxf(c[4 * b + 3] + bv.w, 0.f);
            w[b][0] = (unsigned int)f2b(v0) | ((unsigned int)f2b(v1) << 16);
            w[b][1] = (unsigned int)f2b(v2) | ((unsigned int)f2b(v3) << 16);
        }
        unsigned int p[4][2];
#pragma unroll
        for (int b = 0; b < 4; ++b) {
            p[b][0] = (unsigned int)__shfl_xor((int)w[b][0], 32);
            p[b][1] = (unsigned int)__shfl_xor((int)w[b][1], 32);
        }
        union { unsigned int u[4]; s8b v; } t0, t1;
        t0.u[0] = (h == 0) ? w[0][0] : p[1][0];
        t0.u[1] = (h == 0) ? w[0][1] : p[1][1];
        t0.u[2] = (h == 0) ? p[0][0] : w[1][0];
        t0.u[3] = (h == 0) ? p[0][1] : w[1][1];
        t1.u[0] = (h == 0) ? w[2][0] : p[3][0];
        t1.u[1] = (h == 0) ? w[2][1] : p[3][1];
        t1.u[2] = (h == 0) ? p[2][0] : w[3][0];
        t1.u[3] = (h == 0) ? p[2][1] : w[3][1];
        a2[2 * j]     = t0.v;
        a2[2 * j + 1] = t1.v;
    }
}

__device__ __forceinline__ void gemm2_store(const s8b* __restrict__ sW, const s8b* a2,
                                            const float* __restrict__ b2,
                                            int lane, int h, int row0,
                                            ushort_t* __restrict__ out) {
    const int r32 = lane & 31;
#pragma unroll
    for (int j = 0; j < 4; ++j) {
        f32x16 c;
#pragma unroll
        for (int i = 0; i < 16; ++i) c[i] = 0.f;
#pragma unroll
        for (int ks = 0; ks < 8; ++ks)
            c = __builtin_amdgcn_mfma_f32_32x32x16_bf16(a2[ks], sW[(j * 8 + ks) * 64 + lane], c, 0, 0, 0);
        const int ccol = j * 32 + r32;
        const float bv = b2[ccol];
        const int rbase = row0 + 4 * h;
#pragma unroll
        for (int reg = 0; reg < 16; ++reg) {
            int row = rbase + (reg & 3) + 8 * (reg >> 2);
            out[(size_t)row * HD + ccol] = f2b(fmaxf(c[reg] + bv, 0.f));
        }
    }
}

// ---------------- fused GIN MLP (layer 1): z <- relu(relu(z@W1+b1)@W2+b2)  IN-PLACE ----------------
// 1024 thr = 16 waves, 512 rows/block. W1+W2 both staged (64 KB) -> 2 blocks/CU = 32 waves/CU
// cap (VGPR ~60 <= 64). ONE barrier, then fully wave-independent (round-11 structure).
__global__ __launch_bounds__(1024, 4) void mlp_fused(
    ushort_t* __restrict__ z,
    const ushort_t* __restrict__ Wp1, const ushort_t* __restrict__ Wp2,
    const float* __restrict__ b1, const float* __restrict__ b2)
{
    __shared__ s8b sW1[2048];   // 32 KB
    __shared__ s8b sW2[2048];   // 32 KB

    const int tid = threadIdx.x;
    for (int i = tid; i < 2048; i += 1024) {
        sW1[i] = reinterpret_cast<const s8b*>(Wp1)[i];
        sW2[i] = reinterpret_cast<const s8b*>(Wp2)[i];
    }
    __syncthreads();

    const int lane = tid & 63;
    const int r32  = lane & 31;
    const int h    = lane >> 5;
    const int row0 = blockIdx.x * 512 + (tid >> 6) * 32;
    const int arow = row0 + r32;
    const int koff = h * 8;

    s8b bz[8];
#pragma unroll
    for (int ks = 0; ks < 8; ++ks)
        bz[ks] = *reinterpret_cast<const s8b*>(z + (size_t)arow * HD + ks * 16 + koff);

    s8b a2[8];
    gemm1_repack(sW1, bz, b1, lane, h, a2);
    gemm2_store(sW2, a2, b2, lane, h, row0, z);
}

// ---------------- fully fused GIN layer (layers 2..L): hout = MLP(hin + Σ_nbr hin) ----------------
// Round-11 structure (stage both W's, one barrier, wave-independent gather+GEMMs) at
// 1024 threads: 64 KB LDS x 2 blocks/CU = 32 waves/CU occupancy cap (2x round 11).
__global__ __launch_bounds__(1024, 4) void gin_layer(
    const ushort_t* __restrict__ hin, const int* __restrict__ rowptr,
    const int* __restrict__ col,
    const ushort_t* __restrict__ Wp1, const ushort_t* __restrict__ Wp2,
    const float* __restrict__ b1, const float* __restrict__ b2,
    ushort_t* __restrict__ hout, int n)
{
    __shared__ s8b sW1[2048];   // 32 KB
    __shared__ s8b sW2[2048];   // 32 KB

    const int tid = threadIdx.x;
    for (int i = tid; i < 2048; i += 1024) {
        sW1[i] = reinterpret_cast<const s8b*>(Wp1)[i];
        sW2[i] = reinterpret_cast<const s8b*>(Wp2)[i];
    }
    __syncthreads();            // the ONLY barrier — waves fully independent after

    const int lane = tid & 63;
    const int r32  = lane & 31;
    const int h    = lane >> 5;
    const int row0 = blockIdx.x * 512 + (tid >> 6) * 32;
    const int arow = row0 + r32;
    const int koff = h * 8;

    // ---- fused gather: facc = hin[arow] + Σ_nbr hin[col[i]]  (fp32) -> bf16 frags ----
    s8b bz[8];
    {
        float facc[8][8];
        if (arow < n) {
            const ushort_t* hr = hin + (size_t)arow * HD + koff;
#pragma unroll
            for (int ks = 0; ks < 8; ++ks) {
                us8 v = *reinterpret_cast<const us8*>(hr + ks * 16);
#pragma unroll
                for (int e = 0; e < 8; ++e) facc[ks][e] = b2f(v[e]);
            }
            const int lo = rowptr[arow], hi = rowptr[arow + 1];
            for (int i = lo; i < hi; ++i) {
                const ushort_t* hs = hin + (size_t)col[i] * HD + koff;
#pragma unroll
                for (int ks = 0; ks < 8; ++ks) {
                    us8 v = *reinterpret_cast<const us8*>(hs + ks * 16);
#pragma unroll
                    for (int e = 0; e < 8; ++e) facc[ks][e] += b2f(v[e]);
                }
            }
        } else {
#pragma unroll
            for (int ks = 0; ks < 8; ++ks)
#pragma unroll
                for (int e = 0; e < 8; ++e) facc[ks][e] = 0.f;
        }
#pragma unroll
        for (int ks = 0; ks < 8; ++ks)
#pragma unroll
            for (int e = 0; e < 8; ++e) bz[ks][e] = (short)f2b(facc[ks][e]);
    }

    s8b a2[8];
    gemm1_repack(sW1, bz, b1, lane, h, a2);
    gemm2_store(sW2, a2, b2, lane, h, row0, hout);
}

// ---------------- MFMA GEMM (final projection): out = A[128-blk]@W + b ----------------
template<typename TO, bool RELU>
__global__ __launch_bounds__(256) void gemm_mfma(
    const ushort_t* __restrict__ A, const ushort_t* __restrict__ Wp,
    const float* __restrict__ bias, TO* __restrict__ out, int ldo)
{
    __shared__ s8b sW[2048];    // 32 KB
    const int tid = threadIdx.x;
    for (int i = tid; i < 2048; i += 256)
        sW[i] = reinterpret_cast<const s8b*>(Wp)[i];
    __syncthreads();

    const int lane = tid & 63;
    const int row0 = blockIdx.x * 128 + (tid >> 6) * 32;
    const int arow = row0 + (lane & 31);
    const int koff = (lane >> 5) * 8;

    s8b a[8];
#pragma unroll
    for (int ks = 0; ks < 8; ++ks)
        a[ks] = *reinterpret_cast<const s8b*>(A + (size_t)arow * HD + ks * 16 + koff);

#pragma unroll
    for (int j = 0; j < 4; ++j) {
        f32x16 acc;
#pragma unroll
        for (int i = 0; i < 16; ++i) acc[i] = 0.f;
#pragma unroll
        for (int ks = 0; ks < 8; ++ks)
            acc = __builtin_amdgcn_mfma_f32_32x32x16_bf16(a[ks], sW[(j * 8 + ks) * 64 + lane], acc, 0, 0, 0);
        const int col = j * 32 + (lane & 31);
        const float bv = bias[col];
        const int rbase = row0 + 4 * (lane >> 5);
#pragma unroll
        for (int reg = 0; reg < 16; ++reg) {
            int row = rbase + (reg & 3) + 8 * (reg >> 2);
            float v = acc[reg] + bv;
            if (RELU) v = fmaxf(v, 0.f);
            store1(out + (size_t)row * ldo + col, v);
        }
    }
}

// ---------------- pooling: mean over sorted batch segments ----------------
__global__ __launch_bounds__(128) void pool_kernel(const ushort_t* __restrict__ h,
                                                   const int* __restrict__ batch,
                                                   ushort_t* __restrict__ pooled, int n) {
    int g = blockIdx.x;
    int c = threadIdx.x;   // 128
    int start = lowerb(batch, n, g);
    int end = lowerb(batch, n, g + 1);
    float s = 0.f;
    for (int i = start; i < end; ++i) s += b2f(h[(size_t)i * HD + c]);
    int cnt = end - start; if (cnt < 1) cnt = 1;
    pooled[(size_t)g * HD + c] = f2b(s / (float)cnt);
}

// ---------------- entry ----------------
extern "C" void kernel_launch(void* const* d_in, const int* in_sizes, int n_in,
                              void* d_out, int out_size, void* d_ws, size_t ws_size,
                              hipStream_t stream) {
    const float* x      = (const float*)d_in[0];
    const int*   edge   = (const int*)d_in[1];
    const int*   batch  = (const int*)d_in[2];
    const float* W_enc  = (const float*)d_in[3];
    const float* b_enc  = (const float*)d_in[4];
    const float* W1     = (const float*)d_in[5];
    const float* b1     = (const float*)d_in[6];
    const float* W2     = (const float*)d_in[7];
    const float* b2     = (const float*)d_in[8];
    const float* W_out  = (const float*)d_in[9];
    const float* b_out  = (const float*)d_in[10];

    const int N = in_sizes[0] / 6;
    const int E = in_sizes[1] / 2;
    const int G = out_size / 256;
    const int L = in_sizes[5] / (HD * HD);
    const int Npad = ((N + 511) / 512) * 512;   // 512-row blocks for fused layers

    const int* srcv = edge;
    const int* dstv = edge + E;

    size_t off = 0;
    auto alloc = [&](size_t bytes) -> char* {
        char* p = (char*)d_ws + off;
        off += (bytes + 255) & ~(size_t)255;
        return p;
    };
    ushort_t* bufA   = (ushort_t*)alloc((size_t)Npad * HD * 2);
    ushort_t* bufB   = (ushort_t*)alloc((size_t)Npad * HD * 2);
    ushort_t* pooled = (ushort_t*)alloc((size_t)G * HD * 2);
    ushort_t* Wp1    = (ushort_t*)alloc((size_t)L * 16384 * 2);
    ushort_t* Wp2    = (ushort_t*)alloc((size_t)L * 16384 * 2);
    ushort_t* WpO    = (ushort_t*)alloc((size_t)2 * 16384 * 2);
    float* xaggb = (float*)alloc((size_t)N * 8 * 4);
    int* rowptr = (int*)alloc((size_t)(N + 1) * 4);
    int* cursor = (int*)alloc((size_t)N * 4);
    int* colidx = (int*)alloc((size_t)E * 4);
    int* deg    = (int*)alloc((size_t)N * 4);
    int* bsum   = (int*)alloc((size_t)1024 * 4);
    (void)ws_size;

    // CSR build (parallel 3-phase scan)
    const int nb = (N + SCAN_CHUNK - 1) / SCAN_CHUNK;
    hipMemsetAsync(deg, 0, (size_t)N * 4, stream);
    hist_kernel<<<(E + 255) / 256, 256, 0, stream>>>(dstv, deg, E);
    scan_a<<<nb, SCAN_NT, 0, stream>>>(deg, bsum, N);
    scan_b<<<1, 1024, 0, stream>>>(bsum, nb);
    scan_c<<<nb, SCAN_NT, 0, stream>>>(deg, bsum, rowptr, cursor, N, E);
    fill_kernel<<<(E + 255) / 256, 256, 0, stream>>>(srcv, dstv, cursor, colidx, E);

    // W pre-pack (bf16 fragment order)
    pack_kernel<<<(L * 2048 + 255) / 256, 256, 0, stream>>>(W1, Wp1, L, HD, HD * HD, 0);
    pack_kernel<<<(L * 2048 + 255) / 256, 256, 0, stream>>>(W2, Wp2, L, HD, HD * HD, 0);
    pack_kernel<<<(2 * 2048 + 255) / 256, 256, 0, stream>>>(W_out, WpO, 2, 256, 0, 128);

    // Layer 1: affine fusion — aggregate 6-dim x, one encoder pass, in-place MLP
    xagg_kernel<<<(N + 255) / 256, 256, 0, stream>>>(x, rowptr, colidx, xaggb, N);
    {
        int threads = ((N + 3) / 4) * 16;
        enc2_kernel<<<(threads + 255) / 256, 256, 0, stream>>>(xaggb, W_enc, b_enc, bufA, N);
    }
    const int nblk = Npad / 512;
    mlp_fused<<<nblk, 1024, 0, stream>>>(bufA, Wp1, Wp2, b1, b2);

    // Layers 2..L: fully fused gather+MLP (ping-pong buffers)
    ushort_t* cur = bufA;
    ushort_t* oth = bufB;
    for (int l = 1; l < L; ++l) {
        gin_layer<<<nblk, 1024, 0, stream>>>(
            cur, rowptr, colidx,
            Wp1 + (size_t)l * 16384, Wp2 + (size_t)l * 16384,
            b1 + (size_t)l * HD, b2 + (size_t)l * HD, oth, N);
        ushort_t* t = cur; cur = oth; oth = t;
    }

    // pooling
    pool_kernel<<<G, 128, 0, stream>>>(cur, batch, pooled, N);

    // output GEMM: [G,128] @ [128,256] + b_out -> fp32 d_out (two 128-col halves)
    float* outp = (float*)d_out;
    gemm_mfma<float, false><<<G / 128, 256, 0, stream>>>(pooled, WpO, b_out, outp, 256);
    gemm_mfma<float, false><<<G / 128, 256, 0, stream>>>(pooled, WpO + 16384, b_out + 128, outp + 128, 256);
}

// Round 15
// 463.142 us; speedup vs baseline: 5.5208x; 1.0795x over previous
//
#include <hip/hip_runtime.h>

#define HD 128   // hidden dim

typedef unsigned short ushort_t;
typedef __attribute__((ext_vector_type(8))) unsigned short us8;
typedef __attribute__((ext_vector_type(8))) short s8b;       // 8 bf16 = 4 VGPR (MFMA A/B frag)
typedef __attribute__((ext_vector_type(16))) float f32x16;   // MFMA 32x32 accumulator

// ---------------- bf16 <-> f32 ----------------
__device__ __forceinline__ float b2f(unsigned short u) {
    union { unsigned int i; float f; } v; v.i = ((unsigned int)u) << 16; return v.f;
}
__device__ __forceinline__ unsigned short f2b(float f) {
    union { float f; unsigned int i; } v; v.f = f;
    unsigned int u = v.i;
    return (unsigned short)((u + 0x7fffu + ((u >> 16) & 1u)) >> 16);  // RNE
}
__device__ __forceinline__ unsigned int pk2(float a, float b) {
    return (unsigned int)f2b(a) | ((unsigned int)f2b(b) << 16);
}

__device__ __forceinline__ void load8f(const float* p, float* o) {
    float4 a = *reinterpret_cast<const float4*>(p);
    float4 b = *reinterpret_cast<const float4*>(p + 4);
    o[0]=a.x;o[1]=a.y;o[2]=a.z;o[3]=a.w;o[4]=b.x;o[5]=b.y;o[6]=b.z;o[7]=b.w;
}
__device__ __forceinline__ void store8b(ushort_t* p, const float* s) {
    us8 v;
#pragma unroll
    for (int j = 0; j < 8; ++j) v[j] = f2b(s[j]);
    *reinterpret_cast<us8*>(p) = v;
}

__device__ __forceinline__ void store1(float* p, float v) { *p = v; }
__device__ __forceinline__ void store1(ushort_t* p, float v) { *p = f2b(v); }

__device__ __forceinline__ int lowerb(const int* __restrict__ a, int n, int v) {
    int lo = 0, hi = n;
    while (lo < hi) { int m = (lo + hi) >> 1; if (a[m] < v) lo = m + 1; else hi = m; }
    return lo;
}

// ---------------- CSR build ----------------
__global__ void hist_kernel(const int* __restrict__ dst, int* __restrict__ deg, int e) {
    int i = blockIdx.x * blockDim.x + threadIdx.x;
    if (i < e) atomicAdd(&deg[dst[i]], 1);
}

#define SCAN_NT 256
#define SCAN_BPT 8
#define SCAN_CHUNK (SCAN_NT * SCAN_BPT)   // 2048

__global__ __launch_bounds__(SCAN_NT) void scan_a(const int* __restrict__ deg,
                                                  int* __restrict__ bsum, int n) {
    int tid = threadIdx.x;
    int base = blockIdx.x * SCAN_CHUNK + tid * SCAN_BPT;
    int sum = 0;
    if (base + SCAN_BPT <= n) {
        int4 v0 = *reinterpret_cast<const int4*>(deg + base);
        int4 v1 = *reinterpret_cast<const int4*>(deg + base + 4);
        sum = v0.x + v0.y + v0.z + v0.w + v1.x + v1.y + v1.z + v1.w;
    } else {
        for (int j = 0; j < SCAN_BPT; ++j) { int i = base + j; if (i < n) sum += deg[i]; }
    }
    __shared__ int sd[SCAN_NT];
    sd[tid] = sum; __syncthreads();
    for (int off = SCAN_NT / 2; off > 0; off >>= 1) {
        if (tid < off) sd[tid] += sd[tid + off];
        __syncthreads();
    }
    if (tid == 0) bsum[blockIdx.x] = sd[0];
}

__global__ __launch_bounds__(1024) void scan_b(int* __restrict__ bsum, int nb) {
    __shared__ int ps[1024];
    int tid = threadIdx.x;
    int v = (tid < nb) ? bsum[tid] : 0;
    ps[tid] = v; __syncthreads();
    for (int off = 1; off < 1024; off <<= 1) {
        int t = (tid >= off) ? ps[tid - off] : 0;
        __syncthreads();
        ps[tid] += t;
        __syncthreads();
    }
    if (tid < nb) bsum[tid] = ps[tid] - v;   // exclusive block offsets
}

__global__ __launch_bounds__(SCAN_NT) void scan_c(const int* __restrict__ deg,
                                                  const int* __restrict__ bsum,
                                                  int* __restrict__ rowptr,
                                                  int* __restrict__ cursor,
                                                  int n, int etot) {
    int tid = threadIdx.x;
    int base = blockIdx.x * SCAN_CHUNK + tid * SCAN_BPT;
    int vals[SCAN_BPT];
    if (base + SCAN_BPT <= n) {
        int4 v0 = *reinterpret_cast<const int4*>(deg + base);
        int4 v1 = *reinterpret_cast<const int4*>(deg + base + 4);
        vals[0]=v0.x; vals[1]=v0.y; vals[2]=v0.z; vals[3]=v0.w;
        vals[4]=v1.x; vals[5]=v1.y; vals[6]=v1.z; vals[7]=v1.w;
    } else {
        for (int j = 0; j < SCAN_BPT; ++j) { int i = base + j; vals[j] = (i < n) ? deg[i] : 0; }
    }
    int sum = 0;
#pragma unroll
    for (int j = 0; j < SCAN_BPT; ++j) sum += vals[j];
    __shared__ int ps[SCAN_NT];
    ps[tid] = sum; __syncthreads();
    for (int off = 1; off < SCAN_NT; off <<= 1) {
        int t = (tid >= off) ? ps[tid - off] : 0;
        __syncthreads();
        ps[tid] += t;
        __syncthreads();
    }
    int run = bsum[blockIdx.x] + ps[tid] - sum;
#pragma unroll
    for (int j = 0; j < SCAN_BPT; ++j) {
        int i = base + j;
        if (i < n) { rowptr[i] = run; cursor[i] = run; run += vals[j]; }
    }
    if (blockIdx.x == 0 && tid == 0) rowptr[n] = etot;
}

__global__ void fill_kernel(const int* __restrict__ src, const int* __restrict__ dst,
                            int* __restrict__ cursor, int* __restrict__ col, int e) {
    int i = blockIdx.x * blockDim.x + threadIdx.x;
    if (i < e) { int slot = atomicAdd(&cursor[dst[i]], 1); col[slot] = src[i]; }
}

// ---------------- W pre-pack into MFMA B-fragment order (bf16) ----------------
// flat idx = ((mat*4 + j)*8 + ks)*64 + lane; elem e = W[ks*16+(lane>>5)*8+e][mat*col_off + j*32 + (lane&31)]
// NOTE: B-frag(W) is bit-identical to A-frag(W^T) — used by the swapped GEMM1.
__global__ void pack_kernel(const float* __restrict__ W, ushort_t* __restrict__ Wp,
                            int nmat, int ld, int mat_stride, int col_off) {
    int idx = blockIdx.x * blockDim.x + threadIdx.x;
    if (idx >= nmat * 2048) return;
    int lane = idx & 63;
    int ks = (idx >> 6) & 7;
    int j = (idx >> 9) & 3;
    int mat = idx >> 11;
    const float* Wm = W + (size_t)mat * mat_stride;
    int k0 = ks * 16 + (lane >> 5) * 8;
    int n = mat * col_off + j * 32 + (lane & 31);
    us8 o;
#pragma unroll
    for (int e = 0; e < 8; ++e) o[e] = f2b(Wm[(size_t)(k0 + e) * ld + n]);
    *reinterpret_cast<us8*>(Wp + (size_t)idx * 8) = o;
}

// ---------------- fused x-aggregation: xa[node] = {x[node] + Σ_nbr x[nbr], 1+deg} ----------------
__global__ void xagg_kernel(const float* __restrict__ x, const int* __restrict__ rowptr,
                            const int* __restrict__ col, float* __restrict__ xa, int n) {
    int node = blockIdx.x * blockDim.x + threadIdx.x;
    if (node >= n) return;
    const float2* xr = reinterpret_cast<const float2*>(x + (size_t)node * 6);
    float2 a0 = xr[0], a1 = xr[1], a2 = xr[2];
    int lo = rowptr[node], hi = rowptr[node + 1];
    for (int i = lo; i < hi; ++i) {
        const float2* xs = reinterpret_cast<const float2*>(x + (size_t)col[i] * 6);
        float2 s0 = xs[0], s1 = xs[1], s2 = xs[2];
        a0.x += s0.x; a0.y += s0.y; a1.x += s1.x; a1.y += s1.y; a2.x += s2.x; a2.y += s2.y;
    }
    float cnt = (float)(1 + hi - lo);
    float4 o0; o0.x = a0.x; o0.y = a0.y; o0.z = a1.x; o0.w = a1.y;
    float4 o1; o1.x = a2.x; o1.y = a2.y; o1.z = cnt; o1.w = 0.f;
    reinterpret_cast<float4*>(xa + (size_t)node * 8)[0] = o0;
    reinterpret_cast<float4*>(xa + (size_t)node * 8)[1] = o1;
}

// ---------------- encoder v2: z1 = xa[:, :6] @ W_enc + xa[:,6]·b_enc  (bf16 out) ----------------
__global__ void enc2_kernel(const float* __restrict__ xa, const float* __restrict__ W,
                            const float* __restrict__ b, ushort_t* __restrict__ z, int n) {
    int t = blockIdx.x * blockDim.x + threadIdx.x;
    int q = t >> 4, g = t & 15;
    int node0 = q * 4;
    if (node0 >= n) return;
    float w[6][8];
#pragma unroll
    for (int d = 0; d < 6; ++d) load8f(W + d * HD + g * 8, w[d]);
    float bias[8];
    load8f(b + g * 8, bias);
#pragma unroll
    for (int u = 0; u < 4; ++u) {
        int node = node0 + u;
        if (node >= n) break;
        float4 a0 = reinterpret_cast<const float4*>(xa + (size_t)node * 8)[0];
        float4 a1 = reinterpret_cast<const float4*>(xa + (size_t)node * 8)[1];
        float xv[6] = {a0.x, a0.y, a0.z, a0.w, a1.x, a1.y};
        float cnt = a1.z;
        float acc[8];
#pragma unroll
        for (int j = 0; j < 8; ++j) acc[j] = cnt * bias[j];
#pragma unroll
        for (int d = 0; d < 6; ++d)
#pragma unroll
            for (int j = 0; j < 8; ++j) acc[j] += xv[d] * w[d][j];
        store8b(z + (size_t)node * HD + g * 8, acc);
    }
}

// ---------------- GEMM1(swapped)+repack and GEMM2 helpers ----------------
// Repack uses pairwise shfl (2 blocks at a time) to minimize live temporaries.
__device__ __forceinline__ void gemm1_repack(const s8b* __restrict__ sW, const s8b* bz,
                                             const float* __restrict__ b1,
                                             int lane, int h, s8b* a2) {
#pragma unroll
    for (int j = 0; j < 4; ++j) {
        f32x16 c;
#pragma unroll
        for (int i = 0; i < 16; ++i) c[i] = 0.f;
#pragma unroll
        for (int ks = 0; ks < 8; ++ks)
            c = __builtin_amdgcn_mfma_f32_32x32x16_bf16(sW[(j * 8 + ks) * 64 + lane], bz[ks], c, 0, 0, 0);
        // pair (b=0,1) -> a2[2j]
        {
            float4 bv0 = *reinterpret_cast<const float4*>(b1 + j * 32 + 0  + 4 * h);
            float4 bv1 = *reinterpret_cast<const float4*>(b1 + j * 32 + 8  + 4 * h);
            unsigned int w00 = pk2(fmaxf(c[0] + bv0.x, 0.f), fmaxf(c[1] + bv0.y, 0.f));
            unsigned int w01 = pk2(fmaxf(c[2] + bv0.z, 0.f), fmaxf(c[3] + bv0.w, 0.f));
            unsigned int w10 = pk2(fmaxf(c[4] + bv1.x, 0.f), fmaxf(c[5] + bv1.y, 0.f));
            unsigned int w11 = pk2(fmaxf(c[6] + bv1.z, 0.f), fmaxf(c[7] + bv1.w, 0.f));
            unsigned int p00 = (unsigned int)__shfl_xor((int)w00, 32);
            unsigned int p01 = (unsigned int)__shfl_xor((int)w01, 32);
            unsigned int p10 = (unsigned int)__shfl_xor((int)w10, 32);
            unsigned int p11 = (unsigned int)__shfl_xor((int)w11, 32);
            union { unsigned int u[4]; s8b v; } t;
            t.u[0] = h ? p10 : w00;
            t.u[1] = h ? p11 : w01;
            t.u[2] = h ? w10 : p00;
            t.u[3] = h ? w11 : p01;
            a2[2 * j] = t.v;
        }
        // pair (b=2,3) -> a2[2j+1]
        {
            float4 bv2 = *reinterpret_cast<const float4*>(b1 + j * 32 + 16 + 4 * h);
            float4 bv3 = *reinterpret_cast<const float4*>(b1 + j * 32 + 24 + 4 * h);
            unsigned int w20 = pk2(fmaxf(c[8]  + bv2.x, 0.f), fmaxf(c[9]  + bv2.y, 0.f));
            unsigned int w21 = pk2(fmaxf(c[10] + bv2.z, 0.f), fmaxf(c[11] + bv2.w, 0.f));
            unsigned int w30 = pk2(fmaxf(c[12] + bv3.x, 0.f), fmaxf(c[13] + bv3.y, 0.f));
            unsigned int w31 = pk2(fmaxf(c[14] + bv3.z, 0.f), fmaxf(c[15] + bv3.w, 0.f));
            unsigned int p20 = (unsigned int)__shfl_xor((int)w20, 32);
            unsigned int p21 = (unsigned int)__shfl_xor((int)w21, 32);
            unsigned int p30 = (unsigned int)__shfl_xor((int)w30, 32);
            unsigned int p31 = (unsigned int)__shfl_xor((int)w31, 32);
            union { unsigned int u[4]; s8b v; } t;
            t.u[0] = h ? p30 : w20;
            t.u[1] = h ? p31 : w21;
            t.u[2] = h ? w30 : p20;
            t.u[3] = h ? w31 : p21;
            a2[2 * j + 1] = t.v;
        }
    }
}

__device__ __forceinline__ void gemm2_store(const s8b* __restrict__ sW, const s8b* a2,
                                            const float* __restrict__ b2,
                                            int lane, int h, int row0,
                                            ushort_t* __restrict__ out) {
    const int r32 = lane & 31;
#pragma unroll
    for (int j = 0; j < 4; ++j) {
        f32x16 c;
#pragma unroll
        for (int i = 0; i < 16; ++i) c[i] = 0.f;
#pragma unroll
        for (int ks = 0; ks < 8; ++ks)
            c = __builtin_amdgcn_mfma_f32_32x32x16_bf16(a2[ks], sW[(j * 8 + ks) * 64 + lane], c, 0, 0, 0);
        const int ccol = j * 32 + r32;
        const float bv = b2[ccol];
        const int rbase = row0 + 4 * h;
#pragma unroll
        for (int reg = 0; reg < 16; ++reg) {
            int row = rbase + (reg & 3) + 8 * (reg >> 2);
            out[(size_t)row * HD + ccol] = f2b(fmaxf(c[reg] + bv, 0.f));
        }
    }
}

// ---------------- fused GIN MLP (layer 1): z <- relu(relu(z@W1+b1)@W2+b2)  IN-PLACE ----------------
__global__ __launch_bounds__(1024, 4) void mlp_fused(
    ushort_t* __restrict__ z,
    const ushort_t* __restrict__ Wp1, const ushort_t* __restrict__ Wp2,
    const float* __restrict__ b1, const float* __restrict__ b2)
{
    __shared__ s8b sW1[2048];   // 32 KB
    __shared__ s8b sW2[2048];   // 32 KB

    const int tid = threadIdx.x;
    for (int i = tid; i < 2048; i += 1024) {
        sW1[i] = reinterpret_cast<const s8b*>(Wp1)[i];
        sW2[i] = reinterpret_cast<const s8b*>(Wp2)[i];
    }
    __syncthreads();

    const int lane = tid & 63;
    const int r32  = lane & 31;
    const int h    = lane >> 5;
    const int row0 = blockIdx.x * 512 + (tid >> 6) * 32;
    const int arow = row0 + r32;
    const int koff = h * 8;

    s8b bz[8];
#pragma unroll
    for (int ks = 0; ks < 8; ++ks)
        bz[ks] = *reinterpret_cast<const s8b*>(z + (size_t)arow * HD + ks * 16 + koff);

    s8b a2[8];
    gemm1_repack(sW1, bz, b1, lane, h, a2);
    gemm2_store(sW2, a2, b2, lane, h, row0, z);
}

// ---------------- fully fused GIN layer (layers 2..L): hout = MLP(hin + Σ_nbr hin) ----------------
// SPLIT-PASS gather: two passes of 4 k-slices each (facc 32 f32 instead of 64) to halve
// unified-regfile pressure (the round-11/14 occupancy cap). Pass p reads the contiguous
// 128B half-row [p*128, p*128+128) of each neighbor — total line traffic unchanged,
// colidx read twice (L2-hot). Per-element accumulation order identical -> bit-identical.
__global__ __launch_bounds__(1024, 4) void gin_layer(
    const ushort_t* __restrict__ hin, const int* __restrict__ rowptr,
    const int* __restrict__ col,
    const ushort_t* __restrict__ Wp1, const ushort_t* __restrict__ Wp2,
    const float* __restrict__ b1, const float* __restrict__ b2,
    ushort_t* __restrict__ hout, int n)
{
    __shared__ s8b sW1[2048];   // 32 KB
    __shared__ s8b sW2[2048];   // 32 KB

    const int tid = threadIdx.x;
    for (int i = tid; i < 2048; i += 1024) {
        sW1[i] = reinterpret_cast<const s8b*>(Wp1)[i];
        sW2[i] = reinterpret_cast<const s8b*>(Wp2)[i];
    }
    __syncthreads();            // the ONLY barrier — waves fully independent after

    const int lane = tid & 63;
    const int r32  = lane & 31;
    const int h    = lane >> 5;
    const int row0 = blockIdx.x * 512 + (tid >> 6) * 32;
    const int arow = row0 + r32;
    const int koff = h * 8;

    const bool valid = (arow < n);
    const int lo = valid ? rowptr[arow] : 0;
    const int hi = valid ? rowptr[arow + 1] : 0;
    const ushort_t* hbase = hin + (size_t)arow * HD + koff;

    s8b bz[8];

    // ---- gather pass 0: k-slices 0..3 (bytes [0,128) of each row) ----
    {
        float facc[4][8];
        if (valid) {
#pragma unroll
            for (int q = 0; q < 4; ++q) {
                us8 v = *reinterpret_cast<const us8*>(hbase + q * 16);
#pragma unroll
                for (int e = 0; e < 8; ++e) facc[q][e] = b2f(v[e]);
            }
            for (int i = lo; i < hi; ++i) {
                const ushort_t* hs = hin + (size_t)col[i] * HD + koff;
#pragma unroll
                for (int q = 0; q < 4; ++q) {
                    us8 v = *reinterpret_cast<const us8*>(hs + q * 16);
#pragma unroll
                    for (int e = 0; e < 8; ++e) facc[q][e] += b2f(v[e]);
                }
            }
        } else {
#pragma unroll
            for (int q = 0; q < 4; ++q)
#pragma unroll
                for (int e = 0; e < 8; ++e) facc[q][e] = 0.f;
        }
#pragma unroll
        for (int q = 0; q < 4; ++q)
#pragma unroll
            for (int e = 0; e < 8; ++e) bz[q][e] = (short)f2b(facc[q][e]);
    }

    // ---- gather pass 1: k-slices 4..7 (bytes [128,256) of each row) ----
    {
        float facc[4][8];
        if (valid) {
#pragma unroll
            for (int q = 0; q < 4; ++q) {
                us8 v = *reinterpret_cast<const us8*>(hbase + 64 + q * 16);
#pragma unroll
                for (int e = 0; e < 8; ++e) facc[q][e] = b2f(v[e]);
            }
            for (int i = lo; i < hi; ++i) {
                const ushort_t* hs = hin + (size_t)col[i] * HD + koff + 64;
#pragma unroll
                for (int q = 0; q < 4; ++q) {
                    us8 v = *reinterpret_cast<const us8*>(hs + q * 16);
#pragma unroll
                    for (int e = 0; e < 8; ++e) facc[q][e] += b2f(v[e]);
                }
            }
        } else {
#pragma unroll
            for (int q = 0; q < 4; ++q)
#pragma unroll
                for (int e = 0; e < 8; ++e) facc[q][e] = 0.f;
        }
#pragma unroll
        for (int q = 0; q < 4; ++q)
#pragma unroll
            for (int e = 0; e < 8; ++e) bz[4 + q][e] = (short)f2b(facc[q][e]);
    }

    s8b a2[8];
    gemm1_repack(sW1, bz, b1, lane, h, a2);
    gemm2_store(sW2, a2, b2, lane, h, row0, hout);
}

// ---------------- MFMA GEMM (final projection): out = A[128-blk]@W + b ----------------
template<typename TO, bool RELU>
__global__ __launch_bounds__(256) void gemm_mfma(
    const ushort_t* __restrict__ A, const ushort_t* __restrict__ Wp,
    const float* __restrict__ bias, TO* __restrict__ out, int ldo)
{
    __shared__ s8b sW[2048];    // 32 KB
    const int tid = threadIdx.x;
    for (int i = tid; i < 2048; i += 256)
        sW[i] = reinterpret_cast<const s8b*>(Wp)[i];
    __syncthreads();

    const int lane = tid & 63;
    const int row0 = blockIdx.x * 128 + (tid >> 6) * 32;
    const int arow = row0 + (lane & 31);
    const int koff = (lane >> 5) * 8;

    s8b a[8];
#pragma unroll
    for (int ks = 0; ks < 8; ++ks)
        a[ks] = *reinterpret_cast<const s8b*>(A + (size_t)arow * HD + ks * 16 + koff);

#pragma unroll
    for (int j = 0; j < 4; ++j) {
        f32x16 acc;
#pragma unroll
        for (int i = 0; i < 16; ++i) acc[i] = 0.f;
#pragma unroll
        for (int ks = 0; ks < 8; ++ks)
            acc = __builtin_amdgcn_mfma_f32_32x32x16_bf16(a[ks], sW[(j * 8 + ks) * 64 + lane], acc, 0, 0, 0);
        const int col = j * 32 + (lane & 31);
        const float bv = bias[col];
        const int rbase = row0 + 4 * (lane >> 5);
#pragma unroll
        for (int reg = 0; reg < 16; ++reg) {
            int row = rbase + (reg & 3) + 8 * (reg >> 2);
            float v = acc[reg] + bv;
            if (RELU) v = fmaxf(v, 0.f);
            store1(out + (size_t)row * ldo + col, v);
        }
    }
}

// ---------------- pooling: mean over sorted batch segments ----------------
__global__ __launch_bounds__(128) void pool_kernel(const ushort_t* __restrict__ h,
                                                   const int* __restrict__ batch,
                                                   ushort_t* __restrict__ pooled, int n) {
    int g = blockIdx.x;
    int c = threadIdx.x;   // 128
    int start = lowerb(batch, n, g);
    int end = lowerb(batch, n, g + 1);
    float s = 0.f;
    for (int i = start; i < end; ++i) s += b2f(h[(size_t)i * HD + c]);
    int cnt = end - start; if (cnt < 1) cnt = 1;
    pooled[(size_t)g * HD + c] = f2b(s / (float)cnt);
}

// ---------------- entry ----------------
extern "C" void kernel_launch(void* const* d_in, const int* in_sizes, int n_in,
                              void* d_out, int out_size, void* d_ws, size_t ws_size,
                              hipStream_t stream) {
    const float* x      = (const float*)d_in[0];
    const int*   edge   = (const int*)d_in[1];
    const int*   batch  = (const int*)d_in[2];
    const float* W_enc  = (const float*)d_in[3];
    const float* b_enc  = (const float*)d_in[4];
    const float* W1     = (const float*)d_in[5];
    const float* b1     = (const float*)d_in[6];
    const float* W2     = (const float*)d_in[7];
    const float* b2     = (const float*)d_in[8];
    const float* W_out  = (const float*)d_in[9];
    const float* b_out  = (const float*)d_in[10];

    const int N = in_sizes[0] / 6;
    const int E = in_sizes[1] / 2;
    const int G = out_size / 256;
    const int L = in_sizes[5] / (HD * HD);
    const int Npad = ((N + 511) / 512) * 512;   // 512-row blocks for fused layers

    const int* srcv = edge;
    const int* dstv = edge + E;

    size_t off = 0;
    auto alloc = [&](size_t bytes) -> char* {
        char* p = (char*)d_ws + off;
        off += (bytes + 255) & ~(size_t)255;
        return p;
    };
    ushort_t* bufA   = (ushort_t*)alloc((size_t)Npad * HD * 2);
    ushort_t* bufB   = (ushort_t*)alloc((size_t)Npad * HD * 2);
    ushort_t* pooled = (ushort_t*)alloc((size_t)G * HD * 2);
    ushort_t* Wp1    = (ushort_t*)alloc((size_t)L * 16384 * 2);
    ushort_t* Wp2    = (ushort_t*)alloc((size_t)L * 16384 * 2);
    ushort_t* WpO    = (ushort_t*)alloc((size_t)2 * 16384 * 2);
    float* xaggb = (float*)alloc((size_t)N * 8 * 4);
    int* rowptr = (int*)alloc((size_t)(N + 1) * 4);
    int* cursor = (int*)alloc((size_t)N * 4);
    int* colidx = (int*)alloc((size_t)E * 4);
    int* deg    = (int*)alloc((size_t)N * 4);
    int* bsum   = (int*)alloc((size_t)1024 * 4);
    (void)ws_size;

    // CSR build (parallel 3-phase scan)
    const int nb = (N + SCAN_CHUNK - 1) / SCAN_CHUNK;
    hipMemsetAsync(deg, 0, (size_t)N * 4, stream);
    hist_kernel<<<(E + 255) / 256, 256, 0, stream>>>(dstv, deg, E);
    scan_a<<<nb, SCAN_NT, 0, stream>>>(deg, bsum, N);
    scan_b<<<1, 1024, 0, stream>>>(bsum, nb);
    scan_c<<<nb, SCAN_NT, 0, stream>>>(deg, bsum, rowptr, cursor, N, E);
    fill_kernel<<<(E + 255) / 256, 256, 0, stream>>>(srcv, dstv, cursor, colidx, E);

    // W pre-pack (bf16 fragment order)
    pack_kernel<<<(L * 2048 + 255) / 256, 256, 0, stream>>>(W1, Wp1, L, HD, HD * HD, 0);
    pack_kernel<<<(L * 2048 + 255) / 256, 256, 0, stream>>>(W2, Wp2, L, HD, HD * HD, 0);
    pack_kernel<<<(2 * 2048 + 255) / 256, 256, 0, stream>>>(W_out, WpO, 2, 256, 0, 128);

    // Layer 1: affine fusion — aggregate 6-dim x, one encoder pass, in-place MLP
    xagg_kernel<<<(N + 255) / 256, 256, 0, stream>>>(x, rowptr, colidx, xaggb, N);
    {
        int threads = ((N + 3) / 4) * 16;
        enc2_kernel<<<(threads + 255) / 256, 256, 0, stream>>>(xaggb, W_enc, b_enc, bufA, N);
    }
    const int nblk = Npad / 512;
    mlp_fused<<<nblk, 1024, 0, stream>>>(bufA, Wp1, Wp2, b1, b2);

    // Layers 2..L: fully fused gather+MLP (ping-pong buffers)
    ushort_t* cur = bufA;
    ushort_t* oth = bufB;
    for (int l = 1; l < L; ++l) {
        gin_layer<<<nblk, 1024, 0, stream>>>(
            cur, rowptr, colidx,
            Wp1 + (size_t)l * 16384, Wp2 + (size_t)l * 16384,
            b1 + (size_t)l * HD, b2 + (size_t)l * HD, oth, N);
        ushort_t* t = cur; cur = oth; oth = t;
    }

    // pooling
    pool_kernel<<<G, 128, 0, stream>>>(cur, batch, pooled, N);

    // output GEMM: [G,128] @ [128,256] + b_out -> fp32 d_out (two 128-col halves)
    float* outp = (float*)d_out;
    gemm_mfma<float, false><<<G / 128, 256, 0, stream>>>(pooled, WpO, b_out, outp, 256);
    gemm_mfma<float, false><<<G / 128, 256, 0, stream>>>(pooled, WpO + 16384, b_out + 128, outp + 128, 256);
}